// Round 1
// baseline (1767.550 us; speedup 1.0000x reference)
//
#include <hip/hip_runtime.h>
#include <cstdint>
#include <cmath>

#define NEG_SLOPE 0.2f

__device__ __forceinline__ float leaky(float v) { return v > 0.f ? v : NEG_SLOPE * v; }

// monotone float -> uint mapping for atomicMax-based segment max.
// init value 0 maps below every real float (only -NaN maps to 0).
__device__ __forceinline__ unsigned f2ord(float f) {
    unsigned b = __float_as_uint(f);
    return (b & 0x80000000u) ? ~b : (b | 0x80000000u);
}
__device__ __forceinline__ float ord2f(unsigned u) {
    return (u & 0x80000000u) ? __uint_as_float(u ^ 0x80000000u) : __uint_as_float(~u);
}

// ---------------------------------------------------------------------------
// Fused GEMM + attention-coefficient dots:
//   H[n, :] = X[n, :] @ W          (FIN x FOUT)
//   As[n]   = H[n, :] . a_src
//   Ad[n]   = H[n, :] . a_dst
// Register tile RT rows x 4 cols per thread; W and an X row-tile staged in LDS.
// X rows XOR-swizzled (float4-granular) to avoid ds_read_b128 bank conflicts
// from the power-of-2 row stride.
// ---------------------------------------------------------------------------
template <int FIN, int FOUT, int ROWS, int RT, int LCG>
__global__ __launch_bounds__(256) void gemm_alpha(
    const float* __restrict__ X, const float* __restrict__ W,
    const float* __restrict__ a_src, const float* __restrict__ a_dst,
    float* __restrict__ H, float* __restrict__ As, float* __restrict__ Ad, int N)
{
    constexpr int CG = FOUT / 4;              // column groups (4 cols each)
    static_assert((1 << LCG) == CG, "LCG mismatch");
    static_assert(ROWS * FOUT == 256 * RT * 4, "tile mismatch");

    __shared__ float Ws[FIN * FOUT];
    __shared__ float Xs[ROWS * FIN];

    const int tid = threadIdx.x;
    const int base = blockIdx.x * ROWS;

    // stage W (uniform across blocks, served from L2)
    for (int i = tid; i < FIN * FOUT / 4; i += 256)
        reinterpret_cast<float4*>(Ws)[i] = reinterpret_cast<const float4*>(W)[i];

    // stage X rows, swizzled within each row
    for (int i = tid; i < ROWS * FIN / 4; i += 256) {
        int e4 = i * 4;
        int row = e4 / FIN;
        int k4 = e4 & (FIN - 1);
        float4 v = make_float4(0.f, 0.f, 0.f, 0.f);
        if (base + row < N)
            v = *reinterpret_cast<const float4*>(&X[(size_t)(base + row) * FIN + k4]);
        int pos = row * FIN + (k4 ^ (((row >> 2) & 7) << 2));
        *reinterpret_cast<float4*>(&Xs[pos]) = v;
    }
    __syncthreads();

    const int colg = tid & (CG - 1);
    const int rowg = tid >> LCG;
    const int c0 = colg * 4;
    const int r0 = rowg * RT;

    float acc[RT][4] = {};

    for (int kc = 0; kc < FIN / 4; ++kc) {
        float4 xv[RT];
#pragma unroll
        for (int r = 0; r < RT; ++r) {
            int row = r0 + r;
            int kpos = (kc * 4) ^ (((row >> 2) & 7) << 2);
            xv[r] = *reinterpret_cast<const float4*>(&Xs[row * FIN + kpos]);
        }
        float4 wv0 = *reinterpret_cast<const float4*>(&Ws[(kc * 4 + 0) * FOUT + c0]);
        float4 wv1 = *reinterpret_cast<const float4*>(&Ws[(kc * 4 + 1) * FOUT + c0]);
        float4 wv2 = *reinterpret_cast<const float4*>(&Ws[(kc * 4 + 2) * FOUT + c0]);
        float4 wv3 = *reinterpret_cast<const float4*>(&Ws[(kc * 4 + 3) * FOUT + c0]);
#pragma unroll
        for (int r = 0; r < RT; ++r) {
            float4 xr = xv[r];
            acc[r][0] = fmaf(xr.w, wv3.x, fmaf(xr.z, wv2.x, fmaf(xr.y, wv1.x, fmaf(xr.x, wv0.x, acc[r][0]))));
            acc[r][1] = fmaf(xr.w, wv3.y, fmaf(xr.z, wv2.y, fmaf(xr.y, wv1.y, fmaf(xr.x, wv0.y, acc[r][1]))));
            acc[r][2] = fmaf(xr.w, wv3.z, fmaf(xr.z, wv2.z, fmaf(xr.y, wv1.z, fmaf(xr.x, wv0.z, acc[r][2]))));
            acc[r][3] = fmaf(xr.w, wv3.w, fmaf(xr.z, wv2.w, fmaf(xr.y, wv1.w, fmaf(xr.x, wv0.w, acc[r][3]))));
        }
    }

    // store H
#pragma unroll
    for (int r = 0; r < RT; ++r) {
        int row = base + r0 + r;
        if (row < N)
            *reinterpret_cast<float4*>(&H[(size_t)row * FOUT + c0]) =
                make_float4(acc[r][0], acc[r][1], acc[r][2], acc[r][3]);
    }

    // fused alpha dots: reduce across the CG column-group lanes (consecutive)
    float4 asv = *reinterpret_cast<const float4*>(&a_src[c0]);
    float4 adv = *reinterpret_cast<const float4*>(&a_dst[c0]);
#pragma unroll
    for (int r = 0; r < RT; ++r) {
        float ps = acc[r][0] * asv.x + acc[r][1] * asv.y + acc[r][2] * asv.z + acc[r][3] * asv.w;
        float pd = acc[r][0] * adv.x + acc[r][1] * adv.y + acc[r][2] * adv.z + acc[r][3] * adv.w;
#pragma unroll
        for (int off = 1; off < CG; off <<= 1) {
            ps += __shfl_xor(ps, off);
            pd += __shfl_xor(pd, off);
        }
        if (colg == 0) {
            int row = base + r0 + r;
            if (row < N) { As[row] = ps; Ad[row] = pd; }
        }
    }
}

// ---------------------------------------------------------------------------
// Pass 1: segment max over edges (transformed-uint atomicMax)
// ---------------------------------------------------------------------------
__global__ __launch_bounds__(256) void edge_max(
    const int* __restrict__ src, const int* __restrict__ dst,
    const float* __restrict__ As, const float* __restrict__ Ad,
    unsigned* __restrict__ Mu, int E)
{
    int e = blockIdx.x * 256 + threadIdx.x;
    if (e < E) {
        int s = src[e], d = dst[e];
        float v = leaky(As[s] + Ad[d]);
        atomicMax(&Mu[d], f2ord(v));
    }
}

// fold self-loop score into the max; convert transformed-uint -> float (in place)
__global__ __launch_bounds__(256) void node_selfmax(
    const float* __restrict__ As, const float* __restrict__ Ad,
    unsigned* __restrict__ Mu, float* __restrict__ Mf, int N)
{
    int i = blockIdx.x * 256 + threadIdx.x;
    if (i < N) {
        unsigned u = Mu[i];
        float me = (u == 0u) ? -INFINITY : ord2f(u);
        float es = leaky(As[i] + Ad[i]);
        Mf[i] = fmaxf(me, es);
    }
}

// ---------------------------------------------------------------------------
// Pass 2: per edge w = exp(e - m[dst]); den[dst] += w; acc[dst,:] += w*h[src,:]
// 256 edges staged in LDS, then F-lane groups do the coalesced vector part.
// ---------------------------------------------------------------------------
template <int F>
__global__ __launch_bounds__(256) void edge_aggregate(
    const int* __restrict__ src, const int* __restrict__ dst,
    const float* __restrict__ As, const float* __restrict__ Ad,
    const float* __restrict__ Mf, const float* __restrict__ H,
    float* __restrict__ Den, float* __restrict__ Acc, int E)
{
    __shared__ int ss[256];
    __shared__ int sd[256];
    __shared__ float sw[256];

    const int tid = threadIdx.x;
    int e = blockIdx.x * 256 + tid;
    float w = 0.f; int s = 0, d = 0;
    if (e < E) {
        s = src[e]; d = dst[e];
        float v = leaky(As[s] + Ad[d]);
        w = __expf(v - Mf[d]);            // arg <= 0, no overflow
        atomicAdd(&Den[d], w);
    }
    ss[tid] = s; sd[tid] = d; sw[tid] = w;
    __syncthreads();

    constexpr int G = 256 / F;
    const int lane = tid & (F - 1);
    const int g = tid / F;
    for (int k = g; k < 256; k += G) {
        float wk = sw[k];
        if (wk != 0.f) {
            int sk = ss[k], dk = sd[k];
            atomicAdd(&Acc[(size_t)dk * F + lane], wk * H[(size_t)sk * F + lane]);
        }
    }
}

// ---------------------------------------------------------------------------
// Finalize: fold self-loop in, normalize, add bias, optional ReLU
// ---------------------------------------------------------------------------
template <int F, bool RELU>
__global__ __launch_bounds__(256) void finalize(
    const float* __restrict__ As, const float* __restrict__ Ad,
    const float* __restrict__ Mf, const float* __restrict__ Den,
    const float* __restrict__ Acc, const float* __restrict__ H,
    const float* __restrict__ bias, float* __restrict__ Out, int N)
{
    int idx = blockIdx.x * 256 + threadIdx.x;
    if (idx >= N * F) return;
    int n = idx / F;
    int f = idx & (F - 1);
    float es = leaky(As[n] + Ad[n]);
    float ws = __expf(es - Mf[n]);
    float dt = Den[n] + ws;
    float val = (Acc[idx] + ws * H[idx]) / dt + bias[f];
    if (RELU) val = fmaxf(val, 0.f);
    Out[idx] = val;
}

// ---------------------------------------------------------------------------
extern "C" void kernel_launch(void* const* d_in, const int* in_sizes, int n_in,
                              void* d_out, int out_size, void* d_ws, size_t ws_size,
                              hipStream_t stream)
{
    const float* x   = (const float*)d_in[0];
    const int*   ei  = (const int*)d_in[1];   // [2, E] int32
    const float* W1  = (const float*)d_in[2];
    const float* a1s = (const float*)d_in[3];
    const float* a1d = (const float*)d_in[4];
    const float* b1  = (const float*)d_in[5];
    const float* W2  = (const float*)d_in[6];
    const float* a2s = (const float*)d_in[7];
    const float* a2d = (const float*)d_in[8];
    const float* b2  = (const float*)d_in[9];

    const int N = in_sizes[0] / 128;
    const int E = in_sizes[1] / 2;
    const int* src = ei;
    const int* dst = ei + E;
    float* out = (float*)d_out;

    // workspace layout (floats)
    float* ws = (float*)d_ws;
    size_t o = 0;
    float* h1  = ws + o; o += (size_t)N * 32;
    float* h1a = ws + o; o += (size_t)N * 32;
    float* h2  = ws + o; o += (size_t)N * 64;
    float* as1 = ws + o; o += N;
    float* ad1 = ws + o; o += N;
    float* as2 = ws + o; o += N;
    float* ad2 = ws + o; o += N;
    float* zb   = ws + o;                 // zero-block start
    float* m1   = ws + o; o += N;
    float* den1 = ws + o; o += N;
    float* m2   = ws + o; o += N;
    float* den2 = ws + o; o += N;
    float* acc1 = ws + o; o += (size_t)N * 32;

    // zero per-call state (ws/out are poisoned, not re-zeroed between replays)
    hipMemsetAsync(zb, 0, (size_t)N * 36 * sizeof(float), stream);
    hipMemsetAsync(out, 0, (size_t)N * 64 * sizeof(float), stream);

    const int ge = (E + 255) / 256;

    // ---- layer 1 (FIN=128 -> 32) ----
    gemm_alpha<128, 32, 64, 2, 3><<<(N + 63) / 64, 256, 0, stream>>>(
        x, W1, a1s, a1d, h1, as1, ad1, N);
    edge_max<<<ge, 256, 0, stream>>>(src, dst, as1, ad1, (unsigned*)m1, E);
    node_selfmax<<<(N + 255) / 256, 256, 0, stream>>>(as1, ad1, (unsigned*)m1, m1, N);
    edge_aggregate<32><<<ge, 256, 0, stream>>>(src, dst, as1, ad1, m1, h1, den1, acc1, E);
    finalize<32, true><<<(N * 32 + 255) / 256, 256, 0, stream>>>(
        as1, ad1, m1, den1, acc1, h1, b1, h1a, N);

    // ---- layer 2 (32 -> 64) ----
    gemm_alpha<32, 64, 64, 4, 4><<<(N + 63) / 64, 256, 0, stream>>>(
        h1a, W2, a2s, a2d, h2, as2, ad2, N);
    edge_max<<<ge, 256, 0, stream>>>(src, dst, as2, ad2, (unsigned*)m2, E);
    node_selfmax<<<(N + 255) / 256, 256, 0, stream>>>(as2, ad2, (unsigned*)m2, m2, N);
    edge_aggregate<64><<<ge, 256, 0, stream>>>(src, dst, as2, ad2, m2, h2, den2, out, E);
    finalize<64, false><<<(N * 64 + 255) / 256, 256, 0, stream>>>(
        as2, ad2, m2, den2, out, h2, b2, out, N);
}

// Round 2
// 767.378 us; speedup vs baseline: 2.3034x; 2.3034x over previous
//
#include <hip/hip_runtime.h>
#include <cstdint>
#include <cmath>

#define NEG_SLOPE 0.2f

__device__ __forceinline__ float leaky(float v) { return v > 0.f ? v : NEG_SLOPE * v; }

// ---------------------------------------------------------------------------
// Fused GEMM + attention-coefficient dots:
//   H[n, :] = X[n, :] @ W ;  As[n] = H[n,:].a_src ; Ad[n] = H[n,:].a_dst
// ---------------------------------------------------------------------------
template <int FIN, int FOUT, int ROWS, int RT, int LCG>
__global__ __launch_bounds__(256) void gemm_alpha(
    const float* __restrict__ X, const float* __restrict__ W,
    const float* __restrict__ a_src, const float* __restrict__ a_dst,
    float* __restrict__ H, float* __restrict__ As, float* __restrict__ Ad, int N)
{
    constexpr int CG = FOUT / 4;              // column groups (4 cols each)
    static_assert((1 << LCG) == CG, "LCG mismatch");
    static_assert(ROWS * FOUT == 256 * RT * 4, "tile mismatch");

    __shared__ float Ws[FIN * FOUT];
    __shared__ float Xs[ROWS * FIN];

    const int tid = threadIdx.x;
    const int base = blockIdx.x * ROWS;

    for (int i = tid; i < FIN * FOUT / 4; i += 256)
        reinterpret_cast<float4*>(Ws)[i] = reinterpret_cast<const float4*>(W)[i];

    for (int i = tid; i < ROWS * FIN / 4; i += 256) {
        int e4 = i * 4;
        int row = e4 / FIN;
        int k4 = e4 & (FIN - 1);
        float4 v = make_float4(0.f, 0.f, 0.f, 0.f);
        if (base + row < N)
            v = *reinterpret_cast<const float4*>(&X[(size_t)(base + row) * FIN + k4]);
        int pos = row * FIN + (k4 ^ (((row >> 2) & 7) << 2));
        *reinterpret_cast<float4*>(&Xs[pos]) = v;
    }
    __syncthreads();

    const int colg = tid & (CG - 1);
    const int rowg = tid >> LCG;
    const int c0 = colg * 4;
    const int r0 = rowg * RT;

    float acc[RT][4] = {};

    for (int kc = 0; kc < FIN / 4; ++kc) {
        float4 xv[RT];
#pragma unroll
        for (int r = 0; r < RT; ++r) {
            int row = r0 + r;
            int kpos = (kc * 4) ^ (((row >> 2) & 7) << 2);
            xv[r] = *reinterpret_cast<const float4*>(&Xs[row * FIN + kpos]);
        }
        float4 wv0 = *reinterpret_cast<const float4*>(&Ws[(kc * 4 + 0) * FOUT + c0]);
        float4 wv1 = *reinterpret_cast<const float4*>(&Ws[(kc * 4 + 1) * FOUT + c0]);
        float4 wv2 = *reinterpret_cast<const float4*>(&Ws[(kc * 4 + 2) * FOUT + c0]);
        float4 wv3 = *reinterpret_cast<const float4*>(&Ws[(kc * 4 + 3) * FOUT + c0]);
#pragma unroll
        for (int r = 0; r < RT; ++r) {
            float4 xr = xv[r];
            acc[r][0] = fmaf(xr.w, wv3.x, fmaf(xr.z, wv2.x, fmaf(xr.y, wv1.x, fmaf(xr.x, wv0.x, acc[r][0]))));
            acc[r][1] = fmaf(xr.w, wv3.y, fmaf(xr.z, wv2.y, fmaf(xr.y, wv1.y, fmaf(xr.x, wv0.y, acc[r][1]))));
            acc[r][2] = fmaf(xr.w, wv3.z, fmaf(xr.z, wv2.z, fmaf(xr.y, wv1.z, fmaf(xr.x, wv0.z, acc[r][2]))));
            acc[r][3] = fmaf(xr.w, wv3.w, fmaf(xr.z, wv2.w, fmaf(xr.y, wv1.w, fmaf(xr.x, wv0.w, acc[r][3]))));
        }
    }

#pragma unroll
    for (int r = 0; r < RT; ++r) {
        int row = base + r0 + r;
        if (row < N)
            *reinterpret_cast<float4*>(&H[(size_t)row * FOUT + c0]) =
                make_float4(acc[r][0], acc[r][1], acc[r][2], acc[r][3]);
    }

    float4 asv = *reinterpret_cast<const float4*>(&a_src[c0]);
    float4 adv = *reinterpret_cast<const float4*>(&a_dst[c0]);
#pragma unroll
    for (int r = 0; r < RT; ++r) {
        float ps = acc[r][0] * asv.x + acc[r][1] * asv.y + acc[r][2] * asv.z + acc[r][3] * asv.w;
        float pd = acc[r][0] * adv.x + acc[r][1] * adv.y + acc[r][2] * adv.z + acc[r][3] * adv.w;
#pragma unroll
        for (int off = 1; off < CG; off <<= 1) {
            ps += __shfl_xor(ps, off);
            pd += __shfl_xor(pd, off);
        }
        if (colg == 0) {
            int row = base + r0 + r;
            if (row < N) { As[row] = ps; Ad[row] = pd; }
        }
    }
}

// ---------------------------------------------------------------------------
// CSR build: histogram -> exclusive scan (3 kernels) -> scatter
// ---------------------------------------------------------------------------
__global__ __launch_bounds__(256) void hist_kernel(
    const int* __restrict__ dst, int* __restrict__ deg, int E4)
{
    int i = blockIdx.x * 256 + threadIdx.x;
    if (i < E4) {
        int4 d = reinterpret_cast<const int4*>(dst)[i];
        atomicAdd(&deg[d.x], 1);
        atomicAdd(&deg[d.y], 1);
        atomicAdd(&deg[d.z], 1);
        atomicAdd(&deg[d.w], 1);
    }
}

// block scans 1024 elements (256 threads x 4); input f(i)=deg[i] (0 for i>=N)
__global__ __launch_bounds__(256) void scan1_kernel(
    const int* __restrict__ deg, int* __restrict__ off, int* __restrict__ bsum,
    int N, int M)
{
    __shared__ int sdata[256];
    const int t = threadIdx.x;
    const int base = blockIdx.x * 1024 + t * 4;
    int v[4]; int s = 0;
#pragma unroll
    for (int j = 0; j < 4; ++j) {
        int idx = base + j;
        int d = (idx < N) ? deg[idx] : 0;
        v[j] = d; s += d;
    }
    sdata[t] = s; __syncthreads();
    for (int ofs = 1; ofs < 256; ofs <<= 1) {
        int tmp = (t >= ofs) ? sdata[t - ofs] : 0;
        __syncthreads();
        sdata[t] += tmp;
        __syncthreads();
    }
    int run = sdata[t] - s;  // exclusive prefix of this thread's chunk
#pragma unroll
    for (int j = 0; j < 4; ++j) {
        int idx = base + j;
        if (idx < M) off[idx] = run;
        run += v[j];
    }
    if (t == 255) bsum[blockIdx.x] = sdata[255];
}

__global__ __launch_bounds__(128) void scan2_kernel(int* __restrict__ bsum, int nb)
{
    __shared__ int sd[128];
    int t = threadIdx.x;
    int v = (t < nb) ? bsum[t] : 0;
    sd[t] = v; __syncthreads();
    for (int ofs = 1; ofs < 128; ofs <<= 1) {
        int tmp = (t >= ofs) ? sd[t - ofs] : 0;
        __syncthreads();
        sd[t] += tmp;
        __syncthreads();
    }
    if (t < nb) bsum[t] = sd[t] - v;   // exclusive
}

__global__ __launch_bounds__(256) void scan3_kernel(
    int* __restrict__ off, const int* __restrict__ bsum, int M)
{
    int i = blockIdx.x * 256 + threadIdx.x;
    if (i < M) off[i] += bsum[i >> 10];
}

__global__ __launch_bounds__(256) void scatter_kernel(
    const int* __restrict__ src, const int* __restrict__ dst,
    const int* __restrict__ off, int* __restrict__ cur, int* __restrict__ csr, int E)
{
    int e = blockIdx.x * 256 + threadIdx.x;
    if (e < E) {
        int d = dst[e];
        int p = atomicAdd(&cur[d], 1);
        csr[off[d] + p] = src[e];
    }
}

// ---------------------------------------------------------------------------
// Pull-mode GAT aggregation: one wave per destination node.
// Phase 1: lane-parallel segment max (self-loop folded).
// Phase 2: loop edges, gather h[src] rows, accumulate sum(w*h), sum(w).
// Write: out = acc/den + bias (+ReLU). Zero atomics.
// ---------------------------------------------------------------------------
template <int F, bool RELU>
__global__ __launch_bounds__(256) void gat_aggregate(
    const int* __restrict__ csr, const int* __restrict__ off,
    const float* __restrict__ As, const float* __restrict__ Ad,
    const float* __restrict__ H, const float* __restrict__ bias,
    float* __restrict__ Out, int N)
{
    const int wave = threadIdx.x >> 6;
    const int lane = threadIdx.x & 63;
    const int n = blockIdx.x * 4 + wave;
    if (n >= N) return;

    const int o0 = off[n];
    const int deg = off[n + 1] - o0;
    const float adn = Ad[n];
    const float eself = leaky(As[n] + adn);

    // phase 1: segment max (includes self-loop)
    float m = eself;
    for (int i = lane; i < deg; i += 64) {
        int s = csr[o0 + i];
        m = fmaxf(m, leaky(As[s] + adn));
    }
#pragma unroll
    for (int ofs = 32; ofs; ofs >>= 1) m = fmaxf(m, __shfl_xor(m, ofs));

    if (F == 64) {
        float acc = 0.f, den = 0.f;
#pragma unroll 4
        for (int i = 0; i < deg; ++i) {
            int s = csr[o0 + i];
            float w = __expf(leaky(As[s] + adn) - m);
            acc = fmaf(w, H[(size_t)s * 64 + lane], acc);
            den += w;
        }
        float wsf = __expf(eself - m);
        acc = fmaf(wsf, H[(size_t)n * 64 + lane], acc);
        den += wsf;
        float val = acc / den + bias[lane];
        if (RELU) val = fmaxf(val, 0.f);
        Out[(size_t)n * 64 + lane] = val;
    } else {  // F == 32: two edges per iteration (half-wave each)
        const int half = lane >> 5;
        const int f = lane & 31;
        float acc = 0.f, den = 0.f;
#pragma unroll 2
        for (int i = half; i < deg; i += 2) {
            int s = csr[o0 + i];
            float w = __expf(leaky(As[s] + adn) - m);
            acc = fmaf(w, H[(size_t)s * 32 + f], acc);
            den += w;
        }
        acc += __shfl_xor(acc, 32);
        den += __shfl_xor(den, 32);
        float wsf = __expf(eself - m);
        acc = fmaf(wsf, H[(size_t)n * 32 + f], acc);
        den += wsf;
        if (half == 0) {
            float val = acc / den + bias[f];
            if (RELU) val = fmaxf(val, 0.f);
            Out[(size_t)n * 32 + f] = val;
        }
    }
}

// ---------------------------------------------------------------------------
extern "C" void kernel_launch(void* const* d_in, const int* in_sizes, int n_in,
                              void* d_out, int out_size, void* d_ws, size_t ws_size,
                              hipStream_t stream)
{
    const float* x   = (const float*)d_in[0];
    const int*   ei  = (const int*)d_in[1];   // [2, E] int32
    const float* W1  = (const float*)d_in[2];
    const float* a1s = (const float*)d_in[3];
    const float* a1d = (const float*)d_in[4];
    const float* b1  = (const float*)d_in[5];
    const float* W2  = (const float*)d_in[6];
    const float* a2s = (const float*)d_in[7];
    const float* a2d = (const float*)d_in[8];
    const float* b2  = (const float*)d_in[9];

    const int N = in_sizes[0] / 128;
    const int E = in_sizes[1] / 2;
    const int* src = ei;
    const int* dst = ei + E;
    float* out = (float*)d_out;

    // ---- workspace layout ----
    float* ws = (float*)d_ws;
    size_t o = 0;
    float* h1  = ws + o; o += (size_t)N * 32;
    float* h1a = ws + o; o += (size_t)N * 32;
    float* h2  = ws + o; o += (size_t)N * 64;
    float* as1 = ws + o; o += N;
    float* ad1 = ws + o; o += N;
    float* as2 = ws + o; o += N;
    float* ad2 = ws + o; o += N;
    int* ip = (int*)(ws + o);
    size_t io = 0;
    int* deg  = ip + io; io += N;
    int* cur  = ip + io; io += N;
    int* off  = ip + io; io += (N + 1);
    int* bsum = ip + io; io += 128;
    int* csr  = ip + io; io += E;

    // per-call state init (graph-replay safe): deg & cur are adjacent
    hipMemsetAsync(deg, 0, (size_t)2 * N * sizeof(int), stream);

    const int M = N + 1;
    const int nb = (M + 1023) / 1024;

    // ---- CSR build (by dst), shared by both layers ----
    hist_kernel<<<(E / 4 + 255) / 256, 256, 0, stream>>>(dst, deg, E / 4);
    scan1_kernel<<<nb, 256, 0, stream>>>(deg, off, bsum, N, M);
    scan2_kernel<<<1, 128, 0, stream>>>(bsum, nb);
    scan3_kernel<<<(M + 255) / 256, 256, 0, stream>>>(off, bsum, M);
    scatter_kernel<<<(E + 255) / 256, 256, 0, stream>>>(src, dst, off, cur, csr, E);

    const int gn = (N + 3) / 4;

    // ---- layer 1 (FIN=128 -> 32) ----
    gemm_alpha<128, 32, 64, 2, 3><<<(N + 63) / 64, 256, 0, stream>>>(
        x, W1, a1s, a1d, h1, as1, ad1, N);
    gat_aggregate<32, true><<<gn, 256, 0, stream>>>(
        csr, off, as1, ad1, h1, b1, h1a, N);

    // ---- layer 2 (32 -> 64) ----
    gemm_alpha<32, 64, 64, 4, 4><<<(N + 63) / 64, 256, 0, stream>>>(
        h1a, W2, a2s, a2d, h2, as2, ad2, N);
    gat_aggregate<64, false><<<gn, 256, 0, stream>>>(
        csr, off, as2, ad2, h2, b2, out, N);
}

// Round 3
// 651.666 us; speedup vs baseline: 2.7124x; 1.1776x over previous
//
#include <hip/hip_runtime.h>
#include <cstdint>
#include <cmath>

#define NEG_SLOPE 0.2f
#define BSH 6                 // 64 nodes per bucket
#define BR  64
#define EBUF_CAP 8192         // max edges per bucket staged in LDS (avg ~2048)

__device__ __forceinline__ float leaky(float v) { return v > 0.f ? v : NEG_SLOPE * v; }

// ---------------------------------------------------------------------------
// Fused GEMM + attention-coefficient dots:
//   H[n, :] = X[n, :] @ W ;  As[n] = H[n,:].a_src ; Ad[n] = H[n,:].a_dst
// ---------------------------------------------------------------------------
template <int FIN, int FOUT, int ROWS, int RT, int LCG>
__global__ __launch_bounds__(256) void gemm_alpha(
    const float* __restrict__ X, const float* __restrict__ W,
    const float* __restrict__ a_src, const float* __restrict__ a_dst,
    float* __restrict__ H, float* __restrict__ As, float* __restrict__ Ad, int N)
{
    constexpr int CG = FOUT / 4;              // column groups (4 cols each)
    static_assert((1 << LCG) == CG, "LCG mismatch");
    static_assert(ROWS * FOUT == 256 * RT * 4, "tile mismatch");

    __shared__ float Ws[FIN * FOUT];
    __shared__ float Xs[ROWS * FIN];

    const int tid = threadIdx.x;
    const int base = blockIdx.x * ROWS;

    for (int i = tid; i < FIN * FOUT / 4; i += 256)
        reinterpret_cast<float4*>(Ws)[i] = reinterpret_cast<const float4*>(W)[i];

    for (int i = tid; i < ROWS * FIN / 4; i += 256) {
        int e4 = i * 4;
        int row = e4 / FIN;
        int k4 = e4 & (FIN - 1);
        float4 v = make_float4(0.f, 0.f, 0.f, 0.f);
        if (base + row < N)
            v = *reinterpret_cast<const float4*>(&X[(size_t)(base + row) * FIN + k4]);
        int pos = row * FIN + (k4 ^ (((row >> 2) & 7) << 2));
        *reinterpret_cast<float4*>(&Xs[pos]) = v;
    }
    __syncthreads();

    const int colg = tid & (CG - 1);
    const int rowg = tid >> LCG;
    const int c0 = colg * 4;
    const int r0 = rowg * RT;

    float acc[RT][4] = {};

    for (int kc = 0; kc < FIN / 4; ++kc) {
        float4 xv[RT];
#pragma unroll
        for (int r = 0; r < RT; ++r) {
            int row = r0 + r;
            int kpos = (kc * 4) ^ (((row >> 2) & 7) << 2);
            xv[r] = *reinterpret_cast<const float4*>(&Xs[row * FIN + kpos]);
        }
        float4 wv0 = *reinterpret_cast<const float4*>(&Ws[(kc * 4 + 0) * FOUT + c0]);
        float4 wv1 = *reinterpret_cast<const float4*>(&Ws[(kc * 4 + 1) * FOUT + c0]);
        float4 wv2 = *reinterpret_cast<const float4*>(&Ws[(kc * 4 + 2) * FOUT + c0]);
        float4 wv3 = *reinterpret_cast<const float4*>(&Ws[(kc * 4 + 3) * FOUT + c0]);
#pragma unroll
        for (int r = 0; r < RT; ++r) {
            float4 xr = xv[r];
            acc[r][0] = fmaf(xr.w, wv3.x, fmaf(xr.z, wv2.x, fmaf(xr.y, wv1.x, fmaf(xr.x, wv0.x, acc[r][0]))));
            acc[r][1] = fmaf(xr.w, wv3.y, fmaf(xr.z, wv2.y, fmaf(xr.y, wv1.y, fmaf(xr.x, wv0.y, acc[r][1]))));
            acc[r][2] = fmaf(xr.w, wv3.z, fmaf(xr.z, wv2.z, fmaf(xr.y, wv1.z, fmaf(xr.x, wv0.z, acc[r][2]))));
            acc[r][3] = fmaf(xr.w, wv3.w, fmaf(xr.z, wv2.w, fmaf(xr.y, wv1.w, fmaf(xr.x, wv0.w, acc[r][3]))));
        }
    }

#pragma unroll
    for (int r = 0; r < RT; ++r) {
        int row = base + r0 + r;
        if (row < N)
            *reinterpret_cast<float4*>(&H[(size_t)row * FOUT + c0]) =
                make_float4(acc[r][0], acc[r][1], acc[r][2], acc[r][3]);
    }

    float4 asv = *reinterpret_cast<const float4*>(&a_src[c0]);
    float4 adv = *reinterpret_cast<const float4*>(&a_dst[c0]);
#pragma unroll
    for (int r = 0; r < RT; ++r) {
        float ps = acc[r][0] * asv.x + acc[r][1] * asv.y + acc[r][2] * asv.z + acc[r][3] * asv.w;
        float pd = acc[r][0] * adv.x + acc[r][1] * adv.y + acc[r][2] * adv.z + acc[r][3] * adv.w;
#pragma unroll
        for (int off = 1; off < CG; off <<= 1) {
            ps += __shfl_xor(ps, off);
            pd += __shfl_xor(pd, off);
        }
        if (colg == 0) {
            int row = base + r0 + r;
            if (row < N) { As[row] = ps; Ad[row] = pd; }
        }
    }
}

// ---------------------------------------------------------------------------
// CSR build, bucket-staged for L2 locality.
// Bucket b = dst >> BSH covers nodes [b*64, b*64+64). Edge packed as
// (src << 6) | (dst & 63)  — src < 2^17, fits easily in 31 bits.
// ---------------------------------------------------------------------------
__global__ __launch_bounds__(256) void bucket_hist(
    const int* __restrict__ dst, int* __restrict__ bhist, int E, int NB)
{
    __shared__ int hc[2048];
    for (int i = threadIdx.x; i < 2048; i += 256) hc[i] = 0;
    __syncthreads();
    for (int e = blockIdx.x * 256 + threadIdx.x; e < E; e += gridDim.x * 256)
        atomicAdd(&hc[dst[e] >> BSH], 1);
    __syncthreads();
    for (int i = threadIdx.x; i < NB; i += 256)
        if (hc[i]) atomicAdd(&bhist[i], hc[i]);
}

// single block: exclusive scan of bhist[0..NB) -> boff; init padded tails.
__global__ __launch_bounds__(256) void bucket_scan(
    const int* __restrict__ bhist, int* __restrict__ boff,
    int* __restrict__ btail, int NB)
{
    __shared__ int sd[256];
    const int t = threadIdx.x;
    const int CH = (NB + 255) >> 8;
    int s = 0;
    for (int j = 0; j < CH; ++j) {
        int idx = t * CH + j;
        s += (idx < NB) ? bhist[idx] : 0;
    }
    sd[t] = s; __syncthreads();
    for (int ofs = 1; ofs < 256; ofs <<= 1) {
        int tmp = (t >= ofs) ? sd[t - ofs] : 0;
        __syncthreads();
        sd[t] += tmp;
        __syncthreads();
    }
    int run = sd[t] - s;   // exclusive prefix of this thread's chunk
    for (int j = 0; j < CH; ++j) {
        int idx = t * CH + j;
        if (idx < NB) {
            boff[idx] = run;
            btail[idx * 16] = run;   // padded: one counter per 64B line
            run += bhist[idx];
        }
    }
    if (t == 255) boff[NB] = run;    // == E
}

// scatter packed edges into bucket-contiguous spans of csr[]
__global__ __launch_bounds__(256) void partition_kernel(
    const int* __restrict__ src, const int* __restrict__ dst,
    int* __restrict__ btail, int* __restrict__ csr, int E)
{
    int e = blockIdx.x * 256 + threadIdx.x;
    if (e < E) {
        int d = dst[e];
        int b = d >> BSH;
        int pos = atomicAdd(&btail[b * 16], 1);
        csr[pos] = (src[e] << BSH) | (d & (BR - 1));
    }
}

// one block per bucket: in-place LDS counting sort by node; emits off[] and
// final csr[] (src indices, grouped by dst node).
__global__ __launch_bounds__(256) void bucket_build(
    int* __restrict__ csr, const int* __restrict__ boff,
    int* __restrict__ off, int N, int NB)
{
    __shared__ int ebuf[EBUF_CAP];
    __shared__ int lcnt[BR];
    __shared__ int lpref[BR];
    const int bi = blockIdx.x;
    const int t = threadIdx.x;
    const int nb0 = bi << BSH;
    const int p0 = boff[bi];
    const int p1 = boff[bi + 1];
    const int cnt = p1 - p0;

    if (t < BR) lcnt[t] = 0;
    __syncthreads();
    for (int i = t; i < cnt; i += 256) {
        int v = csr[p0 + i];
        if (i < EBUF_CAP) ebuf[i] = v;
        atomicAdd(&lcnt[v & (BR - 1)], 1);
    }
    __syncthreads();
    if (t < BR) {
        int c = lcnt[t];
        int sc = c;
#pragma unroll
        for (int ofs = 1; ofs < BR; ofs <<= 1) {
            int o = __shfl_up(sc, ofs);
            if (t >= ofs) sc += o;
        }
        lpref[t] = sc - c;                  // exclusive within bucket
        int n = nb0 + t;
        if (n < N) off[n] = p0 + sc - c;
        lcnt[t] = 0;                        // reuse as running cursor
    }
    if (bi == NB - 1 && t == 0) off[N] = p1;
    __syncthreads();
    for (int i = t; i < cnt && i < EBUF_CAP; i += 256) {
        int v = ebuf[i];
        int ln = v & (BR - 1);
        int p = atomicAdd(&lcnt[ln], 1);
        csr[p0 + lpref[ln] + p] = v >> BSH;
    }
}

// ---------------------------------------------------------------------------
// Pull-mode GAT aggregation: one wave per destination node.
// ---------------------------------------------------------------------------
template <int F, bool RELU>
__global__ __launch_bounds__(256) void gat_aggregate(
    const int* __restrict__ csr, const int* __restrict__ off,
    const float* __restrict__ As, const float* __restrict__ Ad,
    const float* __restrict__ H, const float* __restrict__ bias,
    float* __restrict__ Out, int N)
{
    const int wave = threadIdx.x >> 6;
    const int lane = threadIdx.x & 63;
    const int n = blockIdx.x * 4 + wave;
    if (n >= N) return;

    const int o0 = off[n];
    const int deg = off[n + 1] - o0;
    const float adn = Ad[n];
    const float eself = leaky(As[n] + adn);

    // phase 1: segment max (includes self-loop)
    float m = eself;
    for (int i = lane; i < deg; i += 64) {
        int s = csr[o0 + i];
        m = fmaxf(m, leaky(As[s] + adn));
    }
#pragma unroll
    for (int ofs = 32; ofs; ofs >>= 1) m = fmaxf(m, __shfl_xor(m, ofs));

    if (F == 64) {
        float acc = 0.f, den = 0.f;
#pragma unroll 4
        for (int i = 0; i < deg; ++i) {
            int s = csr[o0 + i];
            float w = __expf(leaky(As[s] + adn) - m);
            acc = fmaf(w, H[(size_t)s * 64 + lane], acc);
            den += w;
        }
        float wsf = __expf(eself - m);
        acc = fmaf(wsf, H[(size_t)n * 64 + lane], acc);
        den += wsf;
        float val = acc / den + bias[lane];
        if (RELU) val = fmaxf(val, 0.f);
        Out[(size_t)n * 64 + lane] = val;
    } else {  // F == 32: two edges per iteration (half-wave each)
        const int half = lane >> 5;
        const int f = lane & 31;
        float acc = 0.f, den = 0.f;
#pragma unroll 2
        for (int i = half; i < deg; i += 2) {
            int s = csr[o0 + i];
            float w = __expf(leaky(As[s] + adn) - m);
            acc = fmaf(w, H[(size_t)s * 32 + f], acc);
            den += w;
        }
        acc += __shfl_xor(acc, 32);
        den += __shfl_xor(den, 32);
        float wsf = __expf(eself - m);
        acc = fmaf(wsf, H[(size_t)n * 32 + f], acc);
        den += wsf;
        if (half == 0) {
            float val = acc / den + bias[f];
            if (RELU) val = fmaxf(val, 0.f);
            Out[(size_t)n * 32 + f] = val;
        }
    }
}

// ---------------------------------------------------------------------------
extern "C" void kernel_launch(void* const* d_in, const int* in_sizes, int n_in,
                              void* d_out, int out_size, void* d_ws, size_t ws_size,
                              hipStream_t stream)
{
    const float* x   = (const float*)d_in[0];
    const int*   ei  = (const int*)d_in[1];   // [2, E] int32
    const float* W1  = (const float*)d_in[2];
    const float* a1s = (const float*)d_in[3];
    const float* a1d = (const float*)d_in[4];
    const float* b1  = (const float*)d_in[5];
    const float* W2  = (const float*)d_in[6];
    const float* a2s = (const float*)d_in[7];
    const float* a2d = (const float*)d_in[8];
    const float* b2  = (const float*)d_in[9];

    const int N = in_sizes[0] / 128;
    const int E = in_sizes[1] / 2;
    const int NB = (N + BR - 1) >> BSH;
    const int* src = ei;
    const int* dst = ei + E;
    float* out = (float*)d_out;

    // ---- workspace layout ----
    float* ws = (float*)d_ws;
    size_t o = 0;
    float* h1  = ws + o; o += (size_t)N * 32;
    float* h1a = ws + o; o += (size_t)N * 32;
    float* h2  = ws + o; o += (size_t)N * 64;
    float* as1 = ws + o; o += N;
    float* ad1 = ws + o; o += N;
    float* as2 = ws + o; o += N;
    float* ad2 = ws + o; o += N;
    int* ip = (int*)(ws + o);
    size_t io = 0;
    int* bhist = ip + io; io += NB;
    int* boff  = ip + io; io += (NB + 1);
    int* btail = ip + io; io += (size_t)NB * 16;
    int* off   = ip + io; io += (N + 1);
    int* csr   = ip + io; io += E;

    // per-call state init (graph-replay safe)
    hipMemsetAsync(bhist, 0, (size_t)NB * sizeof(int), stream);

    // ---- CSR build (by dst), shared by both layers ----
    bucket_hist<<<256, 256, 0, stream>>>(dst, bhist, E, NB);
    bucket_scan<<<1, 256, 0, stream>>>(bhist, boff, btail, NB);
    partition_kernel<<<(E + 255) / 256, 256, 0, stream>>>(src, dst, btail, csr, E);
    bucket_build<<<NB, 256, 0, stream>>>(csr, boff, off, N, NB);

    const int gn = (N + 3) / 4;

    // ---- layer 1 (FIN=128 -> 32) ----
    gemm_alpha<128, 32, 64, 2, 3><<<(N + 63) / 64, 256, 0, stream>>>(
        x, W1, a1s, a1d, h1, as1, ad1, N);
    gat_aggregate<32, true><<<gn, 256, 0, stream>>>(
        csr, off, as1, ad1, h1, b1, h1a, N);

    // ---- layer 2 (32 -> 64) ----
    gemm_alpha<32, 64, 64, 4, 4><<<(N + 63) / 64, 256, 0, stream>>>(
        h1a, W2, a2s, a2d, h2, as2, ad2, N);
    gat_aggregate<64, false><<<gn, 256, 0, stream>>>(
        csr, off, as2, ad2, h2, b2, out, N);
}

// Round 4
// 511.829 us; speedup vs baseline: 3.4534x; 1.2732x over previous
//
#include <hip/hip_runtime.h>
#include <cstdint>
#include <cmath>

#define NEG_SLOPE 0.2f
#define BSH 6                 // 64 nodes per fine bucket
#define BR  64
#define CSH 11                // 2048 nodes per coarse bucket (32 fine buckets)
#define EBUF_CAP 8192         // max edges per fine bucket staged in LDS (avg ~2048)
#define PCHUNK 8192           // edges per partition block

__device__ __forceinline__ float leaky(float v) { return v > 0.f ? v : NEG_SLOPE * v; }

// monotone float -> uint mapping for atomicMax-based segment max
__device__ __forceinline__ unsigned f2ord(float f) {
    unsigned b = __float_as_uint(f);
    return (b & 0x80000000u) ? ~b : (b | 0x80000000u);
}
__device__ __forceinline__ float ord2f(unsigned u) {
    return (u & 0x80000000u) ? __uint_as_float(u ^ 0x80000000u) : __uint_as_float(~u);
}

// ---------------------------------------------------------------------------
// Fused GEMM + attention-coefficient dots:
//   H[n, :] = X[n, :] @ W ;  As[n] = H[n,:].a_src ; Ad[n] = H[n,:].a_dst
// ---------------------------------------------------------------------------
template <int FIN, int FOUT, int ROWS, int RT, int LCG>
__global__ __launch_bounds__(256) void gemm_alpha(
    const float* __restrict__ X, const float* __restrict__ W,
    const float* __restrict__ a_src, const float* __restrict__ a_dst,
    float* __restrict__ H, float* __restrict__ As, float* __restrict__ Ad, int N)
{
    constexpr int CG = FOUT / 4;              // column groups (4 cols each)
    static_assert((1 << LCG) == CG, "LCG mismatch");
    static_assert(ROWS * FOUT == 256 * RT * 4, "tile mismatch");

    __shared__ float Ws[FIN * FOUT];
    __shared__ float Xs[ROWS * FIN];

    const int tid = threadIdx.x;
    const int base = blockIdx.x * ROWS;

    for (int i = tid; i < FIN * FOUT / 4; i += 256)
        reinterpret_cast<float4*>(Ws)[i] = reinterpret_cast<const float4*>(W)[i];

    for (int i = tid; i < ROWS * FIN / 4; i += 256) {
        int e4 = i * 4;
        int row = e4 / FIN;
        int k4 = e4 & (FIN - 1);
        float4 v = make_float4(0.f, 0.f, 0.f, 0.f);
        if (base + row < N)
            v = *reinterpret_cast<const float4*>(&X[(size_t)(base + row) * FIN + k4]);
        int pos = row * FIN + (k4 ^ (((row >> 2) & 7) << 2));
        *reinterpret_cast<float4*>(&Xs[pos]) = v;
    }
    __syncthreads();

    const int colg = tid & (CG - 1);
    const int rowg = tid >> LCG;
    const int c0 = colg * 4;
    const int r0 = rowg * RT;

    float acc[RT][4] = {};

    for (int kc = 0; kc < FIN / 4; ++kc) {
        float4 xv[RT];
#pragma unroll
        for (int r = 0; r < RT; ++r) {
            int row = r0 + r;
            int kpos = (kc * 4) ^ (((row >> 2) & 7) << 2);
            xv[r] = *reinterpret_cast<const float4*>(&Xs[row * FIN + kpos]);
        }
        float4 wv0 = *reinterpret_cast<const float4*>(&Ws[(kc * 4 + 0) * FOUT + c0]);
        float4 wv1 = *reinterpret_cast<const float4*>(&Ws[(kc * 4 + 1) * FOUT + c0]);
        float4 wv2 = *reinterpret_cast<const float4*>(&Ws[(kc * 4 + 2) * FOUT + c0]);
        float4 wv3 = *reinterpret_cast<const float4*>(&Ws[(kc * 4 + 3) * FOUT + c0]);
#pragma unroll
        for (int r = 0; r < RT; ++r) {
            float4 xr = xv[r];
            acc[r][0] = fmaf(xr.w, wv3.x, fmaf(xr.z, wv2.x, fmaf(xr.y, wv1.x, fmaf(xr.x, wv0.x, acc[r][0]))));
            acc[r][1] = fmaf(xr.w, wv3.y, fmaf(xr.z, wv2.y, fmaf(xr.y, wv1.y, fmaf(xr.x, wv0.y, acc[r][1]))));
            acc[r][2] = fmaf(xr.w, wv3.z, fmaf(xr.z, wv2.z, fmaf(xr.y, wv1.z, fmaf(xr.x, wv0.z, acc[r][2]))));
            acc[r][3] = fmaf(xr.w, wv3.w, fmaf(xr.z, wv2.w, fmaf(xr.y, wv1.w, fmaf(xr.x, wv0.w, acc[r][3]))));
        }
    }

#pragma unroll
    for (int r = 0; r < RT; ++r) {
        int row = base + r0 + r;
        if (row < N)
            *reinterpret_cast<float4*>(&H[(size_t)row * FOUT + c0]) =
                make_float4(acc[r][0], acc[r][1], acc[r][2], acc[r][3]);
    }

    float4 asv = *reinterpret_cast<const float4*>(&a_src[c0]);
    float4 adv = *reinterpret_cast<const float4*>(&a_dst[c0]);
#pragma unroll
    for (int r = 0; r < RT; ++r) {
        float ps = acc[r][0] * asv.x + acc[r][1] * asv.y + acc[r][2] * asv.z + acc[r][3] * asv.w;
        float pd = acc[r][0] * adv.x + acc[r][1] * adv.y + acc[r][2] * adv.z + acc[r][3] * adv.w;
#pragma unroll
        for (int off = 1; off < CG; off <<= 1) {
            ps += __shfl_xor(ps, off);
            pd += __shfl_xor(pd, off);
        }
        if (colg == 0) {
            int row = base + r0 + r;
            if (row < N) { As[row] = ps; Ad[row] = pd; }
        }
    }
}

// ---------------------------------------------------------------------------
// CSR build: fine histogram -> scan -> two-level locality partition ->
// per-bucket LDS counting sort.
// ---------------------------------------------------------------------------
__global__ __launch_bounds__(256) void bucket_hist(
    const int* __restrict__ dst, int* __restrict__ bhist, int E, int NB)
{
    __shared__ int hc[2048];
    for (int i = threadIdx.x; i < 2048; i += 256) hc[i] = 0;
    __syncthreads();
    for (int e = blockIdx.x * 256 + threadIdx.x; e < E; e += gridDim.x * 256)
        atomicAdd(&hc[dst[e] >> BSH], 1);
    __syncthreads();
    for (int i = threadIdx.x; i < NB; i += 256)
        if (hc[i]) atomicAdd(&bhist[i], hc[i]);
}

// single block: exclusive scan of bhist -> boff; init fine + coarse tails.
__global__ __launch_bounds__(256) void bucket_scan(
    const int* __restrict__ bhist, int* __restrict__ boff,
    int* __restrict__ ftail, int* __restrict__ ctail, int NB, int NC)
{
    __shared__ int sd[256];
    const int t = threadIdx.x;
    const int CH = (NB + 255) >> 8;
    int s = 0;
    for (int j = 0; j < CH; ++j) {
        int idx = t * CH + j;
        s += (idx < NB) ? bhist[idx] : 0;
    }
    sd[t] = s; __syncthreads();
    for (int ofs = 1; ofs < 256; ofs <<= 1) {
        int tmp = (t >= ofs) ? sd[t - ofs] : 0;
        __syncthreads();
        sd[t] += tmp;
        __syncthreads();
    }
    int run = sd[t] - s;   // exclusive prefix of this thread's chunk
    for (int j = 0; j < CH; ++j) {
        int idx = t * CH + j;
        if (idx < NB) {
            boff[idx] = run;
            ftail[idx * 16] = run;
            run += bhist[idx];
        }
    }
    if (t == 255) boff[NB] = run;    // == E
    __syncthreads();
    if (t < NC) {
        int f0 = t << 5;
        ctail[t * 16] = boff[f0 < NB ? f0 : NB];
    }
}

// Pass A: partition into coarse (2048-node) buckets. Block-local histogram +
// one global tail-atomic per bucket -> contiguous ~668B runs per block.
__global__ __launch_bounds__(256) void coarse_partition(
    const int* __restrict__ src, const int* __restrict__ dst,
    int* __restrict__ ctail, int* __restrict__ csrA, int E, int NC)
{
    __shared__ int lhist[64], lcur[64], gpos[64];
    const int t = threadIdx.x;
    if (t < 64) { lhist[t] = 0; lcur[t] = 0; }
    __syncthreads();
    const int base = blockIdx.x * PCHUNK;
    int bb[32], pp[32];
#pragma unroll
    for (int i = 0; i < 32; ++i) {
        int e = base + i * 256 + t;
        bb[i] = -1;
        if (e < E) {
            int sv = src[e], dv = dst[e];
            bb[i] = dv >> CSH;
            pp[i] = (sv << CSH) | (dv & ((1 << CSH) - 1));
            atomicAdd(&lhist[bb[i]], 1);
        }
    }
    __syncthreads();
    if (t < NC && lhist[t]) gpos[t] = atomicAdd(&ctail[t * 16], lhist[t]);
    __syncthreads();
#pragma unroll
    for (int i = 0; i < 32; ++i) {
        if (bb[i] >= 0) {
            int b = bb[i];
            csrA[gpos[b] + atomicAdd(&lcur[b], 1)] = pp[i];
        }
    }
}

// Pass B: within each coarse span, partition into the 32 fine (64-node)
// buckets. Runs of ~1KB; span is L2-resident.
__global__ __launch_bounds__(256) void fine_partition(
    const int* __restrict__ csrA, const int* __restrict__ boff,
    int* __restrict__ ftail, int* __restrict__ csrB, int NB)
{
    __shared__ int lhist[32], lcur[32], gpos[32];
    const int b = blockIdx.x;          // coarse bucket
    const int t = threadIdx.x;
    const int f0 = b << 5;             // first fine bucket of this coarse
    const int fe = (f0 + 32 < NB) ? f0 + 32 : NB;
    const int cstart = boff[f0 < NB ? f0 : NB];
    const int cend = boff[fe];
    const int start = cstart + blockIdx.y * PCHUNK;
    if (start >= cend) return;
    const int end = (start + PCHUNK < cend) ? start + PCHUNK : cend;
    if (t < 32) { lhist[t] = 0; lcur[t] = 0; }
    __syncthreads();
    int ff[32], pp[32];
#pragma unroll
    for (int i = 0; i < 32; ++i) {
        int e = start + i * 256 + t;
        ff[i] = -1;
        if (e < end) {
            int v = csrA[e];
            int sv = v >> CSH, dl = v & ((1 << CSH) - 1);
            ff[i] = dl >> BSH;
            pp[i] = (sv << BSH) | (dl & (BR - 1));
            atomicAdd(&lhist[ff[i]], 1);
        }
    }
    __syncthreads();
    if (t < 32 && lhist[t]) gpos[t] = atomicAdd(&ftail[(f0 + t) * 16], lhist[t]);
    __syncthreads();
#pragma unroll
    for (int i = 0; i < 32; ++i) {
        if (ff[i] >= 0) {
            int f = ff[i];
            csrB[gpos[f] + atomicAdd(&lcur[f], 1)] = pp[i];
        }
    }
}

// one block per fine bucket: in-place LDS counting sort by node; emits off[]
// and final csr[] (src indices, grouped by dst node).
__global__ __launch_bounds__(256) void bucket_build(
    int* __restrict__ csr, const int* __restrict__ boff,
    int* __restrict__ off, int N, int NB)
{
    __shared__ int ebuf[EBUF_CAP];
    __shared__ int lcnt[BR];
    __shared__ int lpref[BR];
    const int bi = blockIdx.x;
    const int t = threadIdx.x;
    const int nb0 = bi << BSH;
    const int p0 = boff[bi];
    const int p1 = boff[bi + 1];
    const int cnt = p1 - p0;

    if (t < BR) lcnt[t] = 0;
    __syncthreads();
    for (int i = t; i < cnt; i += 256) {
        int v = csr[p0 + i];
        if (i < EBUF_CAP) ebuf[i] = v;
        atomicAdd(&lcnt[v & (BR - 1)], 1);
    }
    __syncthreads();
    if (t < BR) {
        int c = lcnt[t];
        int sc = c;
#pragma unroll
        for (int ofs = 1; ofs < BR; ofs <<= 1) {
            int o = __shfl_up(sc, ofs);
            if (t >= ofs) sc += o;
        }
        lpref[t] = sc - c;                  // exclusive within bucket
        int n = nb0 + t;
        if (n < N) off[n] = p0 + sc - c;
        lcnt[t] = 0;                        // reuse as running cursor
    }
    if (bi == NB - 1 && t == 0) off[N] = p1;
    __syncthreads();
    for (int i = t; i < cnt && i < EBUF_CAP; i += 256) {
        int v = ebuf[i];
        int ln = v & (BR - 1);
        int p = atomicAdd(&lcnt[ln], 1);
        csr[p0 + lpref[ln] + p] = v >> BSH;
    }
}

// ---------------------------------------------------------------------------
// Pull-mode GAT aggregation: one wave per destination node.
// ---------------------------------------------------------------------------
template <int F, bool RELU>
__global__ __launch_bounds__(256) void gat_aggregate(
    const int* __restrict__ csr, const int* __restrict__ off,
    const float* __restrict__ As, const float* __restrict__ Ad,
    const float* __restrict__ H, const float* __restrict__ bias,
    float* __restrict__ Out, int N)
{
    const int wave = threadIdx.x >> 6;
    const int lane = threadIdx.x & 63;
    const int n = blockIdx.x * 4 + wave;
    if (n >= N) return;

    const int o0 = off[n];
    const int deg = off[n + 1] - o0;
    const float adn = Ad[n];
    const float eself = leaky(As[n] + adn);

    // phase 1: segment max (includes self-loop)
    float m = eself;
    for (int i = lane; i < deg; i += 64) {
        int s = csr[o0 + i];
        m = fmaxf(m, leaky(As[s] + adn));
    }
#pragma unroll
    for (int ofs = 32; ofs; ofs >>= 1) m = fmaxf(m, __shfl_xor(m, ofs));

    if (F == 64) {
        float acc = 0.f, den = 0.f;
#pragma unroll 4
        for (int i = 0; i < deg; ++i) {
            int s = csr[o0 + i];
            float w = __expf(leaky(As[s] + adn) - m);
            acc = fmaf(w, H[(size_t)s * 64 + lane], acc);
            den += w;
        }
        float wsf = __expf(eself - m);
        acc = fmaf(wsf, H[(size_t)n * 64 + lane], acc);
        den += wsf;
        float val = acc / den + bias[lane];
        if (RELU) val = fmaxf(val, 0.f);
        Out[(size_t)n * 64 + lane] = val;
    } else {  // F == 32: two edges per iteration (half-wave each)
        const int half = lane >> 5;
        const int f = lane & 31;
        float acc = 0.f, den = 0.f;
#pragma unroll 2
        for (int i = half; i < deg; i += 2) {
            int s = csr[o0 + i];
            float w = __expf(leaky(As[s] + adn) - m);
            acc = fmaf(w, H[(size_t)s * 32 + f], acc);
            den += w;
        }
        acc += __shfl_xor(acc, 32);
        den += __shfl_xor(den, 32);
        float wsf = __expf(eself - m);
        acc = fmaf(wsf, H[(size_t)n * 32 + f], acc);
        den += wsf;
        if (half == 0) {
            float val = acc / den + bias[f];
            if (RELU) val = fmaxf(val, 0.f);
            Out[(size_t)n * 32 + f] = val;
        }
    }
}

// ---------------------------------------------------------------------------
extern "C" void kernel_launch(void* const* d_in, const int* in_sizes, int n_in,
                              void* d_out, int out_size, void* d_ws, size_t ws_size,
                              hipStream_t stream)
{
    const float* x   = (const float*)d_in[0];
    const int*   ei  = (const int*)d_in[1];   // [2, E] int32
    const float* W1  = (const float*)d_in[2];
    const float* a1s = (const float*)d_in[3];
    const float* a1d = (const float*)d_in[4];
    const float* b1  = (const float*)d_in[5];
    const float* W2  = (const float*)d_in[6];
    const float* a2s = (const float*)d_in[7];
    const float* a2d = (const float*)d_in[8];
    const float* b2  = (const float*)d_in[9];

    const int N = in_sizes[0] / 128;
    const int E = in_sizes[1] / 2;
    const int NB = (N + BR - 1) >> BSH;
    const int NC = (N + (1 << CSH) - 1) >> CSH;
    const int* src = ei;
    const int* dst = ei + E;
    float* out = (float*)d_out;

    // ---- workspace layout ----
    float* ws = (float*)d_ws;
    size_t o = 0;
    float* h1  = ws + o; o += (size_t)N * 32;
    float* h1a = ws + o; o += (size_t)N * 32;
    float* h2  = ws + o; o += (size_t)N * 64;   // also csrA scratch pre-gemm2
    float* as1 = ws + o; o += N;
    float* ad1 = ws + o; o += N;
    float* as2 = ws + o; o += N;
    float* ad2 = ws + o; o += N;
    int* ip = (int*)(ws + o);
    size_t io = 0;
    int* bhist = ip + io; io += NB;
    int* boff  = ip + io; io += (NB + 1);
    int* ftail = ip + io; io += (size_t)NB * 16;
    int* ctail = ip + io; io += (size_t)NC * 16;
    int* off   = ip + io; io += (N + 1);
    int* csrB  = ip + io; io += E;
    int* csrA  = (int*)h2;                      // E ints fit in N*64 floats

    // per-call state init (graph-replay safe)
    hipMemsetAsync(bhist, 0, (size_t)NB * sizeof(int), stream);

    // ---- CSR build (by dst), shared by both layers ----
    bucket_hist<<<256, 256, 0, stream>>>(dst, bhist, E, NB);
    bucket_scan<<<1, 256, 0, stream>>>(bhist, boff, ftail, ctail, NB, NC);
    coarse_partition<<<(E + PCHUNK - 1) / PCHUNK, 256, 0, stream>>>(
        src, dst, ctail, csrA, E, NC);
    fine_partition<<<dim3(NC, 9), 256, 0, stream>>>(csrA, boff, ftail, csrB, NB);
    bucket_build<<<NB, 256, 0, stream>>>(csrB, boff, off, N, NB);

    const int gn = (N + 3) / 4;

    // ---- layer 1 (FIN=128 -> 32) ----
    gemm_alpha<128, 32, 64, 2, 3><<<(N + 63) / 64, 256, 0, stream>>>(
        x, W1, a1s, a1d, h1, as1, ad1, N);
    gat_aggregate<32, true><<<gn, 256, 0, stream>>>(
        csrB, off, as1, ad1, h1, b1, h1a, N);

    // ---- layer 2 (32 -> 64) ----
    gemm_alpha<32, 64, 64, 4, 4><<<(N + 63) / 64, 256, 0, stream>>>(
        h1a, W2, a2s, a2d, h2, as2, ad2, N);
    gat_aggregate<64, false><<<gn, 256, 0, stream>>>(
        csrB, off, as2, ad2, h2, b2, out, N);
}

// Round 5
// 388.133 us; speedup vs baseline: 4.5540x; 1.3187x over previous
//
#include <hip/hip_runtime.h>
#include <cstdint>
#include <cmath>

#define NEG_SLOPE 0.2f
#define BSH 6                 // 64 nodes per fine bucket
#define BR  64
#define CSH 11                // 2048 nodes per coarse bucket (32 fine buckets)
#define EBUF_CAP 8192         // max edges per fine bucket staged in LDS (avg ~2048)
#define PCHUNK 8192           // edges per partition block

__device__ __forceinline__ float leaky(float v) { return v > 0.f ? v : NEG_SLOPE * v; }

// ---------------------------------------------------------------------------
// Skinny GEMM + attention-coefficient dots, spill-proof formulation:
//   H[n,:] = X[n,:] @ W ;  As[n] = H[n,:].a_src ; Ad[n] = H[n,:].a_dst
// Thread = (row, 4-col group). acc = one float4. CPR threads per row.
// Xs rows padded to FIN+4 floats -> conflict-free ds_read_b128.
// ---------------------------------------------------------------------------
template <int FIN, int FOUT, int CPR, int LCPR>
__global__ __launch_bounds__(256, 4) void gemm_rows(
    const float* __restrict__ X, const float* __restrict__ W,
    const float* __restrict__ a_src, const float* __restrict__ a_dst,
    float* __restrict__ H, float* __restrict__ As, float* __restrict__ Ad, int N)
{
    constexpr int ROWS = 256 / CPR;
    constexpr int XST = FIN + 4;              // padded row stride (floats)
    static_assert((1 << LCPR) == CPR && CPR * 4 == FOUT, "geometry");

    __shared__ float Ws[FIN * FOUT];
    __shared__ float Xs[ROWS * XST];

    const int tid = threadIdx.x;
    const int base = blockIdx.x * ROWS;

    // stage W (small, L2-resident across blocks)
    for (int i = tid; i < FIN * FOUT / 4; i += 256)
        reinterpret_cast<float4*>(Ws)[i] = reinterpret_cast<const float4*>(W)[i];

    // stage X rows into padded LDS
    for (int i = tid; i < ROWS * FIN / 4; i += 256) {
        int row = i / (FIN / 4);
        int k4 = (i - row * (FIN / 4)) * 4;
        float4 v = make_float4(0.f, 0.f, 0.f, 0.f);
        if (base + row < N)
            v = *reinterpret_cast<const float4*>(&X[(size_t)(base + row) * FIN + k4]);
        *reinterpret_cast<float4*>(&Xs[row * XST + k4]) = v;
    }
    __syncthreads();

    const int colg = tid & (CPR - 1);
    const int row = tid >> LCPR;
    const int c0 = colg * 4;

    float4 acc = make_float4(0.f, 0.f, 0.f, 0.f);

#pragma unroll 2
    for (int k = 0; k < FIN; k += 4) {
        float4 xv = *reinterpret_cast<const float4*>(&Xs[row * XST + k]);
        float4 w0 = *reinterpret_cast<const float4*>(&Ws[(k + 0) * FOUT + c0]);
        float4 w1 = *reinterpret_cast<const float4*>(&Ws[(k + 1) * FOUT + c0]);
        float4 w2 = *reinterpret_cast<const float4*>(&Ws[(k + 2) * FOUT + c0]);
        float4 w3 = *reinterpret_cast<const float4*>(&Ws[(k + 3) * FOUT + c0]);
        acc.x = fmaf(xv.w, w3.x, fmaf(xv.z, w2.x, fmaf(xv.y, w1.x, fmaf(xv.x, w0.x, acc.x))));
        acc.y = fmaf(xv.w, w3.y, fmaf(xv.z, w2.y, fmaf(xv.y, w1.y, fmaf(xv.x, w0.y, acc.y))));
        acc.z = fmaf(xv.w, w3.z, fmaf(xv.z, w2.z, fmaf(xv.y, w1.z, fmaf(xv.x, w0.z, acc.z))));
        acc.w = fmaf(xv.w, w3.w, fmaf(xv.z, w2.w, fmaf(xv.y, w1.w, fmaf(xv.x, w0.w, acc.w))));
    }

    const int grow = base + row;
    if (grow < N)
        *reinterpret_cast<float4*>(&H[(size_t)grow * FOUT + c0]) = acc;

    // alpha dots: reduce across the CPR consecutive lanes of this row
    float4 asv = *reinterpret_cast<const float4*>(&a_src[c0]);
    float4 adv = *reinterpret_cast<const float4*>(&a_dst[c0]);
    float ps = acc.x * asv.x + acc.y * asv.y + acc.z * asv.z + acc.w * asv.w;
    float pd = acc.x * adv.x + acc.y * adv.y + acc.z * adv.z + acc.w * adv.w;
#pragma unroll
    for (int ofs = 1; ofs < CPR; ofs <<= 1) {
        ps += __shfl_xor(ps, ofs);
        pd += __shfl_xor(pd, ofs);
    }
    if (colg == 0 && grow < N) { As[grow] = ps; Ad[grow] = pd; }
}

// ---------------------------------------------------------------------------
// CSR build: fine histogram -> scan -> two-level locality partition ->
// per-bucket LDS counting sort.
// ---------------------------------------------------------------------------
__global__ __launch_bounds__(256) void bucket_hist(
    const int* __restrict__ dst, int* __restrict__ bhist, int E, int NB)
{
    __shared__ int hc[2048];
    for (int i = threadIdx.x; i < 2048; i += 256) hc[i] = 0;
    __syncthreads();
    for (int e = blockIdx.x * 256 + threadIdx.x; e < E; e += gridDim.x * 256)
        atomicAdd(&hc[dst[e] >> BSH], 1);
    __syncthreads();
    for (int i = threadIdx.x; i < NB; i += 256)
        if (hc[i]) atomicAdd(&bhist[i], hc[i]);
}

// single block: exclusive scan of bhist -> boff; init fine + coarse tails.
__global__ __launch_bounds__(256) void bucket_scan(
    const int* __restrict__ bhist, int* __restrict__ boff,
    int* __restrict__ ftail, int* __restrict__ ctail, int NB, int NC)
{
    __shared__ int sd[256];
    const int t = threadIdx.x;
    const int CH = (NB + 255) >> 8;
    int s = 0;
    for (int j = 0; j < CH; ++j) {
        int idx = t * CH + j;
        s += (idx < NB) ? bhist[idx] : 0;
    }
    sd[t] = s; __syncthreads();
    for (int ofs = 1; ofs < 256; ofs <<= 1) {
        int tmp = (t >= ofs) ? sd[t - ofs] : 0;
        __syncthreads();
        sd[t] += tmp;
        __syncthreads();
    }
    int run = sd[t] - s;   // exclusive prefix of this thread's chunk
    for (int j = 0; j < CH; ++j) {
        int idx = t * CH + j;
        if (idx < NB) {
            boff[idx] = run;
            ftail[idx * 16] = run;
            run += bhist[idx];
        }
    }
    if (t == 255) boff[NB] = run;    // == E
    __syncthreads();
    if (t < NC) {
        int f0 = t << 5;
        ctail[t * 16] = boff[f0 < NB ? f0 : NB];
    }
}

// Pass A: partition into coarse (2048-node) buckets. Block-local histogram +
// one global tail-atomic per bucket -> contiguous runs per block.
__global__ __launch_bounds__(256) void coarse_partition(
    const int* __restrict__ src, const int* __restrict__ dst,
    int* __restrict__ ctail, int* __restrict__ csrA, int E, int NC)
{
    __shared__ int lhist[64], lcur[64], gpos[64];
    const int t = threadIdx.x;
    if (t < 64) { lhist[t] = 0; lcur[t] = 0; }
    __syncthreads();
    const int base = blockIdx.x * PCHUNK;
    int bb[32], pp[32];
#pragma unroll
    for (int i = 0; i < 32; ++i) {
        int e = base + i * 256 + t;
        bb[i] = -1;
        if (e < E) {
            int sv = src[e], dv = dst[e];
            bb[i] = dv >> CSH;
            pp[i] = (sv << CSH) | (dv & ((1 << CSH) - 1));
            atomicAdd(&lhist[bb[i]], 1);
        }
    }
    __syncthreads();
    if (t < NC && lhist[t]) gpos[t] = atomicAdd(&ctail[t * 16], lhist[t]);
    __syncthreads();
#pragma unroll
    for (int i = 0; i < 32; ++i) {
        if (bb[i] >= 0) {
            int b = bb[i];
            csrA[gpos[b] + atomicAdd(&lcur[b], 1)] = pp[i];
        }
    }
}

// Pass B: within each coarse span, partition into the 32 fine (64-node)
// buckets. Runs of ~1KB; span is L2-resident.
__global__ __launch_bounds__(256) void fine_partition(
    const int* __restrict__ csrA, const int* __restrict__ boff,
    int* __restrict__ ftail, int* __restrict__ csrB, int NB)
{
    __shared__ int lhist[32], lcur[32], gpos[32];
    const int b = blockIdx.x;          // coarse bucket
    const int t = threadIdx.x;
    const int f0 = b << 5;             // first fine bucket of this coarse
    const int fe = (f0 + 32 < NB) ? f0 + 32 : NB;
    const int cstart = boff[f0 < NB ? f0 : NB];
    const int cend = boff[fe];
    const int start = cstart + blockIdx.y * PCHUNK;
    if (start >= cend) return;
    const int end = (start + PCHUNK < cend) ? start + PCHUNK : cend;
    if (t < 32) { lhist[t] = 0; lcur[t] = 0; }
    __syncthreads();
    int ff[32], pp[32];
#pragma unroll
    for (int i = 0; i < 32; ++i) {
        int e = start + i * 256 + t;
        ff[i] = -1;
        if (e < end) {
            int v = csrA[e];
            int sv = v >> CSH, dl = v & ((1 << CSH) - 1);
            ff[i] = dl >> BSH;
            pp[i] = (sv << BSH) | (dl & (BR - 1));
            atomicAdd(&lhist[ff[i]], 1);
        }
    }
    __syncthreads();
    if (t < 32 && lhist[t]) gpos[t] = atomicAdd(&ftail[(f0 + t) * 16], lhist[t]);
    __syncthreads();
#pragma unroll
    for (int i = 0; i < 32; ++i) {
        if (ff[i] >= 0) {
            int f = ff[i];
            csrB[gpos[f] + atomicAdd(&lcur[f], 1)] = pp[i];
        }
    }
}

// one block per fine bucket: in-place LDS counting sort by node; emits off[]
// and final csr[] (src indices, grouped by dst node).
__global__ __launch_bounds__(256) void bucket_build(
    int* __restrict__ csr, const int* __restrict__ boff,
    int* __restrict__ off, int N, int NB)
{
    __shared__ int ebuf[EBUF_CAP];
    __shared__ int lcnt[BR];
    __shared__ int lpref[BR];
    const int bi = blockIdx.x;
    const int t = threadIdx.x;
    const int nb0 = bi << BSH;
    const int p0 = boff[bi];
    const int p1 = boff[bi + 1];
    const int cnt = p1 - p0;

    if (t < BR) lcnt[t] = 0;
    __syncthreads();
    for (int i = t; i < cnt; i += 256) {
        int v = csr[p0 + i];
        if (i < EBUF_CAP) ebuf[i] = v;
        atomicAdd(&lcnt[v & (BR - 1)], 1);
    }
    __syncthreads();
    if (t < BR) {
        int c = lcnt[t];
        int sc = c;
#pragma unroll
        for (int ofs = 1; ofs < BR; ofs <<= 1) {
            int o = __shfl_up(sc, ofs);
            if (t >= ofs) sc += o;
        }
        lpref[t] = sc - c;                  // exclusive within bucket
        int n = nb0 + t;
        if (n < N) off[n] = p0 + sc - c;
        lcnt[t] = 0;                        // reuse as running cursor
    }
    if (bi == NB - 1 && t == 0) off[N] = p1;
    __syncthreads();
    for (int i = t; i < cnt && i < EBUF_CAP; i += 256) {
        int v = ebuf[i];
        int ln = v & (BR - 1);
        int p = atomicAdd(&lcnt[ln], 1);
        csr[p0 + lpref[ln] + p] = v >> BSH;
    }
}

// ---------------------------------------------------------------------------
// Pull-mode GAT aggregation: one wave per destination node.
// ---------------------------------------------------------------------------
template <int F, bool RELU>
__global__ __launch_bounds__(256) void gat_aggregate(
    const int* __restrict__ csr, const int* __restrict__ off,
    const float* __restrict__ As, const float* __restrict__ Ad,
    const float* __restrict__ H, const float* __restrict__ bias,
    float* __restrict__ Out, int N)
{
    const int wave = threadIdx.x >> 6;
    const int lane = threadIdx.x & 63;
    const int n = blockIdx.x * 4 + wave;
    if (n >= N) return;

    const int o0 = off[n];
    const int deg = off[n + 1] - o0;
    const float adn = Ad[n];
    const float eself = leaky(As[n] + adn);

    // phase 1: segment max (includes self-loop)
    float m = eself;
    for (int i = lane; i < deg; i += 64) {
        int s = csr[o0 + i];
        m = fmaxf(m, leaky(As[s] + adn));
    }
#pragma unroll
    for (int ofs = 32; ofs; ofs >>= 1) m = fmaxf(m, __shfl_xor(m, ofs));

    if (F == 64) {
        float acc = 0.f, den = 0.f;
#pragma unroll 4
        for (int i = 0; i < deg; ++i) {
            int s = csr[o0 + i];
            float w = __expf(leaky(As[s] + adn) - m);
            acc = fmaf(w, H[(size_t)s * 64 + lane], acc);
            den += w;
        }
        float wsf = __expf(eself - m);
        acc = fmaf(wsf, H[(size_t)n * 64 + lane], acc);
        den += wsf;
        float val = acc / den + bias[lane];
        if (RELU) val = fmaxf(val, 0.f);
        Out[(size_t)n * 64 + lane] = val;
    } else {  // F == 32: two edges per iteration (half-wave each)
        const int half = lane >> 5;
        const int f = lane & 31;
        float acc = 0.f, den = 0.f;
#pragma unroll 2
        for (int i = half; i < deg; i += 2) {
            int s = csr[o0 + i];
            float w = __expf(leaky(As[s] + adn) - m);
            acc = fmaf(w, H[(size_t)s * 32 + f], acc);
            den += w;
        }
        acc += __shfl_xor(acc, 32);
        den += __shfl_xor(den, 32);
        float wsf = __expf(eself - m);
        acc = fmaf(wsf, H[(size_t)n * 32 + f], acc);
        den += wsf;
        if (half == 0) {
            float val = acc / den + bias[f];
            if (RELU) val = fmaxf(val, 0.f);
            Out[(size_t)n * 32 + f] = val;
        }
    }
}

// ---------------------------------------------------------------------------
extern "C" void kernel_launch(void* const* d_in, const int* in_sizes, int n_in,
                              void* d_out, int out_size, void* d_ws, size_t ws_size,
                              hipStream_t stream)
{
    const float* x   = (const float*)d_in[0];
    const int*   ei  = (const int*)d_in[1];   // [2, E] int32
    const float* W1  = (const float*)d_in[2];
    const float* a1s = (const float*)d_in[3];
    const float* a1d = (const float*)d_in[4];
    const float* b1  = (const float*)d_in[5];
    const float* W2  = (const float*)d_in[6];
    const float* a2s = (const float*)d_in[7];
    const float* a2d = (const float*)d_in[8];
    const float* b2  = (const float*)d_in[9];

    const int N = in_sizes[0] / 128;
    const int E = in_sizes[1] / 2;
    const int NB = (N + BR - 1) >> BSH;
    const int NC = (N + (1 << CSH) - 1) >> CSH;
    const int* src = ei;
    const int* dst = ei + E;
    float* out = (float*)d_out;

    // ---- workspace layout ----
    float* ws = (float*)d_ws;
    size_t o = 0;
    float* h1  = ws + o; o += (size_t)N * 32;
    float* h1a = ws + o; o += (size_t)N * 32;
    float* h2  = ws + o; o += (size_t)N * 64;   // also csrA scratch pre-gemm2
    float* as1 = ws + o; o += N;
    float* ad1 = ws + o; o += N;
    float* as2 = ws + o; o += N;
    float* ad2 = ws + o; o += N;
    int* ip = (int*)(ws + o);
    size_t io = 0;
    int* bhist = ip + io; io += NB;
    int* boff  = ip + io; io += (NB + 1);
    int* ftail = ip + io; io += (size_t)NB * 16;
    int* ctail = ip + io; io += (size_t)NC * 16;
    int* off   = ip + io; io += (N + 1);
    int* csrB  = ip + io; io += E;
    int* csrA  = (int*)h2;                      // E ints fit in N*64 floats

    // per-call state init (graph-replay safe)
    hipMemsetAsync(bhist, 0, (size_t)NB * sizeof(int), stream);

    // ---- CSR build (by dst), shared by both layers ----
    bucket_hist<<<256, 256, 0, stream>>>(dst, bhist, E, NB);
    bucket_scan<<<1, 256, 0, stream>>>(bhist, boff, ftail, ctail, NB, NC);
    coarse_partition<<<(E + PCHUNK - 1) / PCHUNK, 256, 0, stream>>>(
        src, dst, ctail, csrA, E, NC);
    fine_partition<<<dim3(NC, 9), 256, 0, stream>>>(csrA, boff, ftail, csrB, NB);
    bucket_build<<<NB, 256, 0, stream>>>(csrB, boff, off, N, NB);

    const int gn = (N + 3) / 4;

    // ---- layer 1 (FIN=128 -> 32) ----
    gemm_rows<128, 32, 8, 3><<<(N + 31) / 32, 256, 0, stream>>>(
        x, W1, a1s, a1d, h1, as1, ad1, N);
    gat_aggregate<32, true><<<gn, 256, 0, stream>>>(
        csrB, off, as1, ad1, h1, b1, h1a, N);

    // ---- layer 2 (32 -> 64) ----
    gemm_rows<32, 64, 16, 4><<<(N + 15) / 16, 256, 0, stream>>>(
        h1a, W2, a2s, a2d, h2, as2, ad2, N);
    gat_aggregate<64, false><<<gn, 256, 0, stream>>>(
        csrB, off, as2, ad2, h2, b2, out, N);
}

// Round 6
// 337.540 us; speedup vs baseline: 5.2366x; 1.1499x over previous
//
#include <hip/hip_runtime.h>
#include <cstdint>
#include <cmath>

#define NEG_SLOPE 0.2f
#define BSH 6                 // 64 nodes per fine bucket
#define BR  64
#define CSH 11                // 2048 nodes per coarse bucket (32 fine buckets)
#define EBUF_CAP 8192         // max edges per fine bucket staged in LDS (avg ~2048)
#define PCHUNK 8192           // edges per partition block

__device__ __forceinline__ float leaky(float v) { return v > 0.f ? v : NEG_SLOPE * v; }
__device__ __forceinline__ float uf(unsigned u) { return __uint_as_float(u); }

// ---------------------------------------------------------------------------
// Skinny GEMM + attention-coefficient dots, spill-proof formulation:
//   H[n,:] = X[n,:] @ W ;  As[n] = H[n,:].a_src ; Ad[n] = H[n,:].a_dst
// ---------------------------------------------------------------------------
template <int FIN, int FOUT, int CPR, int LCPR>
__global__ __launch_bounds__(256, 4) void gemm_rows(
    const float* __restrict__ X, const float* __restrict__ W,
    const float* __restrict__ a_src, const float* __restrict__ a_dst,
    float* __restrict__ H, float* __restrict__ As, float* __restrict__ Ad, int N)
{
    constexpr int ROWS = 256 / CPR;
    constexpr int XST = FIN + 4;              // padded row stride (floats)
    static_assert((1 << LCPR) == CPR && CPR * 4 == FOUT, "geometry");

    __shared__ float Ws[FIN * FOUT];
    __shared__ float Xs[ROWS * XST];

    const int tid = threadIdx.x;
    const int base = blockIdx.x * ROWS;

    for (int i = tid; i < FIN * FOUT / 4; i += 256)
        reinterpret_cast<float4*>(Ws)[i] = reinterpret_cast<const float4*>(W)[i];

    for (int i = tid; i < ROWS * FIN / 4; i += 256) {
        int row = i / (FIN / 4);
        int k4 = (i - row * (FIN / 4)) * 4;
        float4 v = make_float4(0.f, 0.f, 0.f, 0.f);
        if (base + row < N)
            v = *reinterpret_cast<const float4*>(&X[(size_t)(base + row) * FIN + k4]);
        *reinterpret_cast<float4*>(&Xs[row * XST + k4]) = v;
    }
    __syncthreads();

    const int colg = tid & (CPR - 1);
    const int row = tid >> LCPR;
    const int c0 = colg * 4;

    float4 acc = make_float4(0.f, 0.f, 0.f, 0.f);

#pragma unroll 2
    for (int k = 0; k < FIN; k += 4) {
        float4 xv = *reinterpret_cast<const float4*>(&Xs[row * XST + k]);
        float4 w0 = *reinterpret_cast<const float4*>(&Ws[(k + 0) * FOUT + c0]);
        float4 w1 = *reinterpret_cast<const float4*>(&Ws[(k + 1) * FOUT + c0]);
        float4 w2 = *reinterpret_cast<const float4*>(&Ws[(k + 2) * FOUT + c0]);
        float4 w3 = *reinterpret_cast<const float4*>(&Ws[(k + 3) * FOUT + c0]);
        acc.x = fmaf(xv.w, w3.x, fmaf(xv.z, w2.x, fmaf(xv.y, w1.x, fmaf(xv.x, w0.x, acc.x))));
        acc.y = fmaf(xv.w, w3.y, fmaf(xv.z, w2.y, fmaf(xv.y, w1.y, fmaf(xv.x, w0.y, acc.y))));
        acc.z = fmaf(xv.w, w3.z, fmaf(xv.z, w2.z, fmaf(xv.y, w1.z, fmaf(xv.x, w0.z, acc.z))));
        acc.w = fmaf(xv.w, w3.w, fmaf(xv.z, w2.w, fmaf(xv.y, w1.w, fmaf(xv.x, w0.w, acc.w))));
    }

    const int grow = base + row;
    if (grow < N)
        *reinterpret_cast<float4*>(&H[(size_t)grow * FOUT + c0]) = acc;

    float4 asv = *reinterpret_cast<const float4*>(&a_src[c0]);
    float4 adv = *reinterpret_cast<const float4*>(&a_dst[c0]);
    float ps = acc.x * asv.x + acc.y * asv.y + acc.z * asv.z + acc.w * asv.w;
    float pd = acc.x * adv.x + acc.y * adv.y + acc.z * adv.z + acc.w * adv.w;
#pragma unroll
    for (int ofs = 1; ofs < CPR; ofs <<= 1) {
        ps += __shfl_xor(ps, ofs);
        pd += __shfl_xor(pd, ofs);
    }
    if (colg == 0 && grow < N) { As[grow] = ps; Ad[grow] = pd; }
}

// ---------------------------------------------------------------------------
// CSR build: fine histogram -> scan -> two-level locality partition ->
// per-bucket LDS counting sort.
// ---------------------------------------------------------------------------
__global__ __launch_bounds__(256) void bucket_hist(
    const int* __restrict__ dst, int* __restrict__ bhist, int E, int NB)
{
    __shared__ int hc[2048];
    for (int i = threadIdx.x; i < 2048; i += 256) hc[i] = 0;
    __syncthreads();
    for (int e = blockIdx.x * 256 + threadIdx.x; e < E; e += gridDim.x * 256)
        atomicAdd(&hc[dst[e] >> BSH], 1);
    __syncthreads();
    for (int i = threadIdx.x; i < NB; i += 256)
        if (hc[i]) atomicAdd(&bhist[i], hc[i]);
}

__global__ __launch_bounds__(256) void bucket_scan(
    const int* __restrict__ bhist, int* __restrict__ boff,
    int* __restrict__ ftail, int* __restrict__ ctail, int NB, int NC)
{
    __shared__ int sd[256];
    const int t = threadIdx.x;
    const int CH = (NB + 255) >> 8;
    int s = 0;
    for (int j = 0; j < CH; ++j) {
        int idx = t * CH + j;
        s += (idx < NB) ? bhist[idx] : 0;
    }
    sd[t] = s; __syncthreads();
    for (int ofs = 1; ofs < 256; ofs <<= 1) {
        int tmp = (t >= ofs) ? sd[t - ofs] : 0;
        __syncthreads();
        sd[t] += tmp;
        __syncthreads();
    }
    int run = sd[t] - s;
    for (int j = 0; j < CH; ++j) {
        int idx = t * CH + j;
        if (idx < NB) {
            boff[idx] = run;
            ftail[idx * 16] = run;
            run += bhist[idx];
        }
    }
    if (t == 255) boff[NB] = run;    // == E
    __syncthreads();
    if (t < NC) {
        int f0 = t << 5;
        ctail[t * 16] = boff[f0 < NB ? f0 : NB];
    }
}

__global__ __launch_bounds__(256) void coarse_partition(
    const int* __restrict__ src, const int* __restrict__ dst,
    int* __restrict__ ctail, int* __restrict__ csrA, int E, int NC)
{
    __shared__ int lhist[64], lcur[64], gpos[64];
    const int t = threadIdx.x;
    if (t < 64) { lhist[t] = 0; lcur[t] = 0; }
    __syncthreads();
    const int base = blockIdx.x * PCHUNK;
    int bb[32], pp[32];
#pragma unroll
    for (int i = 0; i < 32; ++i) {
        int e = base + i * 256 + t;
        bb[i] = -1;
        if (e < E) {
            int sv = src[e], dv = dst[e];
            bb[i] = dv >> CSH;
            pp[i] = (sv << CSH) | (dv & ((1 << CSH) - 1));
            atomicAdd(&lhist[bb[i]], 1);
        }
    }
    __syncthreads();
    if (t < NC && lhist[t]) gpos[t] = atomicAdd(&ctail[t * 16], lhist[t]);
    __syncthreads();
#pragma unroll
    for (int i = 0; i < 32; ++i) {
        if (bb[i] >= 0) {
            int b = bb[i];
            csrA[gpos[b] + atomicAdd(&lcur[b], 1)] = pp[i];
        }
    }
}

__global__ __launch_bounds__(256) void fine_partition(
    const int* __restrict__ csrA, const int* __restrict__ boff,
    int* __restrict__ ftail, int* __restrict__ csrB, int NB)
{
    __shared__ int lhist[32], lcur[32], gpos[32];
    const int b = blockIdx.x;
    const int t = threadIdx.x;
    const int f0 = b << 5;
    const int fe = (f0 + 32 < NB) ? f0 + 32 : NB;
    const int cstart = boff[f0 < NB ? f0 : NB];
    const int cend = boff[fe];
    const int start = cstart + blockIdx.y * PCHUNK;
    if (start >= cend) return;
    const int end = (start + PCHUNK < cend) ? start + PCHUNK : cend;
    if (t < 32) { lhist[t] = 0; lcur[t] = 0; }
    __syncthreads();
    int ff[32], pp[32];
#pragma unroll
    for (int i = 0; i < 32; ++i) {
        int e = start + i * 256 + t;
        ff[i] = -1;
        if (e < end) {
            int v = csrA[e];
            int sv = v >> CSH, dl = v & ((1 << CSH) - 1);
            ff[i] = dl >> BSH;
            pp[i] = (sv << BSH) | (dl & (BR - 1));
            atomicAdd(&lhist[ff[i]], 1);
        }
    }
    __syncthreads();
    if (t < 32 && lhist[t]) gpos[t] = atomicAdd(&ftail[(f0 + t) * 16], lhist[t]);
    __syncthreads();
#pragma unroll
    for (int i = 0; i < 32; ++i) {
        if (ff[i] >= 0) {
            int f = ff[i];
            csrB[gpos[f] + atomicAdd(&lcur[f], 1)] = pp[i];
        }
    }
}

__global__ __launch_bounds__(256) void bucket_build(
    int* __restrict__ csr, const int* __restrict__ boff,
    int* __restrict__ off, int N, int NB)
{
    __shared__ int ebuf[EBUF_CAP];
    __shared__ int lcnt[BR];
    __shared__ int lpref[BR];
    const int bi = blockIdx.x;
    const int t = threadIdx.x;
    const int nb0 = bi << BSH;
    const int p0 = boff[bi];
    const int p1 = boff[bi + 1];
    const int cnt = p1 - p0;

    if (t < BR) lcnt[t] = 0;
    __syncthreads();
    for (int i = t; i < cnt; i += 256) {
        int v = csr[p0 + i];
        if (i < EBUF_CAP) ebuf[i] = v;
        atomicAdd(&lcnt[v & (BR - 1)], 1);
    }
    __syncthreads();
    if (t < BR) {
        int c = lcnt[t];
        int sc = c;
#pragma unroll
        for (int ofs = 1; ofs < BR; ofs <<= 1) {
            int o = __shfl_up(sc, ofs);
            if (t >= ofs) sc += o;
        }
        lpref[t] = sc - c;
        int n = nb0 + t;
        if (n < N) off[n] = p0 + sc - c;
        lcnt[t] = 0;
    }
    if (bi == NB - 1 && t == 0) off[N] = p1;
    __syncthreads();
    for (int i = t; i < cnt && i < EBUF_CAP; i += 256) {
        int v = ebuf[i];
        int ln = v & (BR - 1);
        int p = atomicAdd(&lcnt[ln], 1);
        csr[p0 + lpref[ln] + p] = v >> BSH;
    }
}

// ---------------------------------------------------------------------------
// Pull-mode GAT aggregation, chunked: per 64-edge chunk, lanes compute w in
// parallel into LDS (uint2 = {byte offset of src row, w}); serial gather loop
// is then just ds_read_b64 + global_load_dword + fmac, 4-way unrolled.
// ---------------------------------------------------------------------------
template <int F, bool RELU>
__global__ __launch_bounds__(256) void gat_aggregate(
    const int* __restrict__ csr, const int* __restrict__ off,
    const float* __restrict__ As, const float* __restrict__ Ad,
    const float* __restrict__ H, const float* __restrict__ bias,
    float* __restrict__ Out, int N)
{
    __shared__ uint2 pr[4][64];
    const int wave = threadIdx.x >> 6;
    const int lane = threadIdx.x & 63;
    const int n = blockIdx.x * 4 + wave;
    if (n >= N) return;

    const int o0 = off[n];
    const int deg = off[n + 1] - o0;
    const float adn = Ad[n];
    const float eself = leaky(As[n] + adn);

    // phase 1: segment max (includes self-loop), lane-parallel
    float m = eself;
    for (int i = lane; i < deg; i += 64) {
        int s = csr[o0 + i];
        m = fmaxf(m, leaky(As[s] + adn));
    }
#pragma unroll
    for (int ofs = 32; ofs; ofs >>= 1) m = fmaxf(m, __shfl_xor(m, ofs));

    uint2* myp = pr[wave];
    const char* Hc = (const char*)H;
    float denp = 0.f;

    if (F == 64) {
        const unsigned lane4 = lane * 4;
        float acc0 = 0.f, acc1 = 0.f;
        for (int c = 0; c < deg; c += 64) {
            int i = c + lane;
            float w = 0.f; unsigned sb = 0;
            if (i < deg) {
                int s = csr[o0 + i];
                w = __expf(leaky(As[s] + adn) - m);
                sb = (unsigned)s * 256u;
                denp += w;
            }
            myp[lane] = make_uint2(sb, __float_as_uint(w));
            int lim = (deg - c < 64) ? deg - c : 64;
            int j = 0;
            for (; j + 4 <= lim; j += 4) {
                uint2 p0 = myp[j], p1 = myp[j + 1], p2 = myp[j + 2], p3 = myp[j + 3];
                float v0 = *(const float*)(Hc + p0.x + lane4);
                float v1 = *(const float*)(Hc + p1.x + lane4);
                float v2 = *(const float*)(Hc + p2.x + lane4);
                float v3 = *(const float*)(Hc + p3.x + lane4);
                acc0 = fmaf(uf(p0.y), v0, acc0);
                acc1 = fmaf(uf(p1.y), v1, acc1);
                acc0 = fmaf(uf(p2.y), v2, acc0);
                acc1 = fmaf(uf(p3.y), v3, acc1);
            }
            for (; j < lim; ++j) {
                uint2 p = myp[j];
                acc0 = fmaf(uf(p.y), *(const float*)(Hc + p.x + lane4), acc0);
            }
        }
        float acc = acc0 + acc1;
#pragma unroll
        for (int ofs = 1; ofs < 64; ofs <<= 1) denp += __shfl_xor(denp, ofs);
        float wsf = __expf(eself - m);
        acc = fmaf(wsf, H[(size_t)n * 64 + lane], acc);
        float den = denp + wsf;
        float val = acc / den + bias[lane];
        if (RELU) val = fmaxf(val, 0.f);
        Out[(size_t)n * 64 + lane] = val;
    } else {  // F == 32: half-waves process alternating edges
        const int half = lane >> 5;
        const int f = lane & 31;
        const unsigned lane4 = f * 4;
        float acc0 = 0.f, acc1 = 0.f;
        for (int c = 0; c < deg; c += 64) {
            int i = c + lane;
            float w = 0.f; unsigned sb = 0;
            if (i < deg) {
                int s = csr[o0 + i];
                w = __expf(leaky(As[s] + adn) - m);
                sb = (unsigned)s * 128u;
                denp += w;
            }
            myp[lane] = make_uint2(sb, __float_as_uint(w));
            int lim = (deg - c < 64) ? deg - c : 64;
            int jj = 0;
            for (; jj + 8 <= lim; jj += 8) {
                uint2 p0 = myp[jj + half],     p1 = myp[jj + 2 + half];
                uint2 p2 = myp[jj + 4 + half], p3 = myp[jj + 6 + half];
                float v0 = *(const float*)(Hc + p0.x + lane4);
                float v1 = *(const float*)(Hc + p1.x + lane4);
                float v2 = *(const float*)(Hc + p2.x + lane4);
                float v3 = *(const float*)(Hc + p3.x + lane4);
                acc0 = fmaf(uf(p0.y), v0, acc0);
                acc1 = fmaf(uf(p1.y), v1, acc1);
                acc0 = fmaf(uf(p2.y), v2, acc0);
                acc1 = fmaf(uf(p3.y), v3, acc1);
            }
            for (; jj < lim; jj += 2) {
                int j = jj + half;
                if (j < lim) {
                    uint2 p = myp[j];
                    acc0 = fmaf(uf(p.y), *(const float*)(Hc + p.x + lane4), acc0);
                }
            }
        }
        float acc = acc0 + acc1;
        acc += __shfl_xor(acc, 32);
#pragma unroll
        for (int ofs = 1; ofs < 64; ofs <<= 1) denp += __shfl_xor(denp, ofs);
        float wsf = __expf(eself - m);
        acc = fmaf(wsf, H[(size_t)n * 32 + f], acc);
        float den = denp + wsf;
        if (half == 0) {
            float val = acc / den + bias[f];
            if (RELU) val = fmaxf(val, 0.f);
            Out[(size_t)n * 32 + f] = val;
        }
    }
}

// ---------------------------------------------------------------------------
extern "C" void kernel_launch(void* const* d_in, const int* in_sizes, int n_in,
                              void* d_out, int out_size, void* d_ws, size_t ws_size,
                              hipStream_t stream)
{
    const float* x   = (const float*)d_in[0];
    const int*   ei  = (const int*)d_in[1];   // [2, E] int32
    const float* W1  = (const float*)d_in[2];
    const float* a1s = (const float*)d_in[3];
    const float* a1d = (const float*)d_in[4];
    const float* b1  = (const float*)d_in[5];
    const float* W2  = (const float*)d_in[6];
    const float* a2s = (const float*)d_in[7];
    const float* a2d = (const float*)d_in[8];
    const float* b2  = (const float*)d_in[9];

    const int N = in_sizes[0] / 128;
    const int E = in_sizes[1] / 2;
    const int NB = (N + BR - 1) >> BSH;
    const int NC = (N + (1 << CSH) - 1) >> CSH;
    const int* src = ei;
    const int* dst = ei + E;
    float* out = (float*)d_out;

    // ---- workspace layout ----
    float* ws = (float*)d_ws;
    size_t o = 0;
    float* h1  = ws + o; o += (size_t)N * 32;
    float* h1a = ws + o; o += (size_t)N * 32;
    float* h2  = ws + o; o += (size_t)N * 64;   // also csrA scratch pre-gemm2
    float* as1 = ws + o; o += N;
    float* ad1 = ws + o; o += N;
    float* as2 = ws + o; o += N;
    float* ad2 = ws + o; o += N;
    int* ip = (int*)(ws + o);
    size_t io = 0;
    int* bhist = ip + io; io += NB;
    int* boff  = ip + io; io += (NB + 1);
    int* ftail = ip + io; io += (size_t)NB * 16;
    int* ctail = ip + io; io += (size_t)NC * 16;
    int* off   = ip + io; io += (N + 1);
    int* csrB  = ip + io; io += E;
    int* csrA  = (int*)h2;                      // E ints fit in N*64 floats

    // per-call state init (graph-replay safe)
    hipMemsetAsync(bhist, 0, (size_t)NB * sizeof(int), stream);

    // ---- CSR build (by dst), shared by both layers ----
    bucket_hist<<<256, 256, 0, stream>>>(dst, bhist, E, NB);
    bucket_scan<<<1, 256, 0, stream>>>(bhist, boff, ftail, ctail, NB, NC);
    coarse_partition<<<(E + PCHUNK - 1) / PCHUNK, 256, 0, stream>>>(
        src, dst, ctail, csrA, E, NC);
    fine_partition<<<dim3(NC, 9), 256, 0, stream>>>(csrA, boff, ftail, csrB, NB);
    bucket_build<<<NB, 256, 0, stream>>>(csrB, boff, off, N, NB);

    const int gn = (N + 3) / 4;

    // ---- layer 1 (FIN=128 -> 32) ----
    gemm_rows<128, 32, 8, 3><<<(N + 31) / 32, 256, 0, stream>>>(
        x, W1, a1s, a1d, h1, as1, ad1, N);
    gat_aggregate<32, true><<<gn, 256, 0, stream>>>(
        csrB, off, as1, ad1, h1, b1, h1a, N);

    // ---- layer 2 (32 -> 64) ----
    gemm_rows<32, 64, 16, 4><<<(N + 15) / 16, 256, 0, stream>>>(
        h1a, W2, a2s, a2d, h2, as2, ad2, N);
    gat_aggregate<64, false><<<gn, 256, 0, stream>>>(
        csrB, off, as2, ad2, h2, b2, out, N);
}

// Round 7
// 286.587 us; speedup vs baseline: 6.1676x; 1.1778x over previous
//
#include <hip/hip_runtime.h>
#include <cstdint>
#include <cmath>

#define NEG_SLOPE 0.2f
#define BSH 6                 // 64 nodes per fine bucket
#define BR  64
#define CSH 11                // 2048 nodes per coarse bucket (32 fine buckets)
#define EBUF_CAP 8192         // max edges per fine bucket staged in LDS (avg ~2048)
#define PCHUNK 8192           // edges per partition block

__device__ __forceinline__ float leaky(float v) { return v > 0.f ? v : NEG_SLOPE * v; }
__device__ __forceinline__ float uf(unsigned u) { return __uint_as_float(u); }

// f32 -> bf16 with round-to-nearest-even (finite inputs)
__device__ __forceinline__ unsigned short f2bf(float f) {
    unsigned u = __float_as_uint(f);
    unsigned r = ((u >> 16) & 1u) + 0x7fffu;
    return (unsigned short)((u + r) >> 16);
}
// unpack a pair of bf16 from one dword: lo = bits[15:0], hi = bits[31:16]
__device__ __forceinline__ float bflo(unsigned q) { return __uint_as_float(q << 16); }
__device__ __forceinline__ float bfhi(unsigned q) { return __uint_as_float(q & 0xffff0000u); }

// ---------------------------------------------------------------------------
// Skinny GEMM + attention-coefficient dots, spill-proof formulation:
//   H[n,:] = bf16(X[n,:] @ W) ;  As[n]/Ad[n] from full-precision acc.
// ---------------------------------------------------------------------------
template <int FIN, int FOUT, int CPR, int LCPR>
__global__ __launch_bounds__(256, 4) void gemm_rows(
    const float* __restrict__ X, const float* __restrict__ W,
    const float* __restrict__ a_src, const float* __restrict__ a_dst,
    unsigned short* __restrict__ H, float* __restrict__ As, float* __restrict__ Ad,
    int N)
{
    constexpr int ROWS = 256 / CPR;
    constexpr int XST = FIN + 4;              // padded row stride (floats)
    static_assert((1 << LCPR) == CPR && CPR * 4 == FOUT, "geometry");

    __shared__ float Ws[FIN * FOUT];
    __shared__ float Xs[ROWS * XST];

    const int tid = threadIdx.x;
    const int base = blockIdx.x * ROWS;

    for (int i = tid; i < FIN * FOUT / 4; i += 256)
        reinterpret_cast<float4*>(Ws)[i] = reinterpret_cast<const float4*>(W)[i];

    for (int i = tid; i < ROWS * FIN / 4; i += 256) {
        int row = i / (FIN / 4);
        int k4 = (i - row * (FIN / 4)) * 4;
        float4 v = make_float4(0.f, 0.f, 0.f, 0.f);
        if (base + row < N)
            v = *reinterpret_cast<const float4*>(&X[(size_t)(base + row) * FIN + k4]);
        *reinterpret_cast<float4*>(&Xs[row * XST + k4]) = v;
    }
    __syncthreads();

    const int colg = tid & (CPR - 1);
    const int row = tid >> LCPR;
    const int c0 = colg * 4;

    float4 acc = make_float4(0.f, 0.f, 0.f, 0.f);

#pragma unroll 2
    for (int k = 0; k < FIN; k += 4) {
        float4 xv = *reinterpret_cast<const float4*>(&Xs[row * XST + k]);
        float4 w0 = *reinterpret_cast<const float4*>(&Ws[(k + 0) * FOUT + c0]);
        float4 w1 = *reinterpret_cast<const float4*>(&Ws[(k + 1) * FOUT + c0]);
        float4 w2 = *reinterpret_cast<const float4*>(&Ws[(k + 2) * FOUT + c0]);
        float4 w3 = *reinterpret_cast<const float4*>(&Ws[(k + 3) * FOUT + c0]);
        acc.x = fmaf(xv.w, w3.x, fmaf(xv.z, w2.x, fmaf(xv.y, w1.x, fmaf(xv.x, w0.x, acc.x))));
        acc.y = fmaf(xv.w, w3.y, fmaf(xv.z, w2.y, fmaf(xv.y, w1.y, fmaf(xv.x, w0.y, acc.y))));
        acc.z = fmaf(xv.w, w3.z, fmaf(xv.z, w2.z, fmaf(xv.y, w1.z, fmaf(xv.x, w0.z, acc.z))));
        acc.w = fmaf(xv.w, w3.w, fmaf(xv.z, w2.w, fmaf(xv.y, w1.w, fmaf(xv.x, w0.w, acc.w))));
    }

    const int grow = base + row;
    if (grow < N) {
        ushort4 hv;
        hv.x = f2bf(acc.x); hv.y = f2bf(acc.y);
        hv.z = f2bf(acc.z); hv.w = f2bf(acc.w);
        *reinterpret_cast<ushort4*>(&H[(size_t)grow * FOUT + c0]) = hv;
    }

    float4 asv = *reinterpret_cast<const float4*>(&a_src[c0]);
    float4 adv = *reinterpret_cast<const float4*>(&a_dst[c0]);
    float ps = acc.x * asv.x + acc.y * asv.y + acc.z * asv.z + acc.w * asv.w;
    float pd = acc.x * adv.x + acc.y * adv.y + acc.z * adv.z + acc.w * adv.w;
#pragma unroll
    for (int ofs = 1; ofs < CPR; ofs <<= 1) {
        ps += __shfl_xor(ps, ofs);
        pd += __shfl_xor(pd, ofs);
    }
    if (colg == 0 && grow < N) { As[grow] = ps; Ad[grow] = pd; }
}

// ---------------------------------------------------------------------------
// CSR build: fine histogram -> scan -> two-level locality partition ->
// per-bucket LDS counting sort.
// ---------------------------------------------------------------------------
__global__ __launch_bounds__(256) void bucket_hist(
    const int* __restrict__ dst, int* __restrict__ bhist, int E, int NB)
{
    __shared__ int hc[2048];
    for (int i = threadIdx.x; i < 2048; i += 256) hc[i] = 0;
    __syncthreads();
    for (int e = blockIdx.x * 256 + threadIdx.x; e < E; e += gridDim.x * 256)
        atomicAdd(&hc[dst[e] >> BSH], 1);
    __syncthreads();
    for (int i = threadIdx.x; i < NB; i += 256)
        if (hc[i]) atomicAdd(&bhist[i], hc[i]);
}

__global__ __launch_bounds__(256) void bucket_scan(
    const int* __restrict__ bhist, int* __restrict__ boff,
    int* __restrict__ ftail, int* __restrict__ ctail, int NB, int NC)
{
    __shared__ int sd[256];
    const int t = threadIdx.x;
    const int CH = (NB + 255) >> 8;
    int s = 0;
    for (int j = 0; j < CH; ++j) {
        int idx = t * CH + j;
        s += (idx < NB) ? bhist[idx] : 0;
    }
    sd[t] = s; __syncthreads();
    for (int ofs = 1; ofs < 256; ofs <<= 1) {
        int tmp = (t >= ofs) ? sd[t - ofs] : 0;
        __syncthreads();
        sd[t] += tmp;
        __syncthreads();
    }
    int run = sd[t] - s;
    for (int j = 0; j < CH; ++j) {
        int idx = t * CH + j;
        if (idx < NB) {
            boff[idx] = run;
            ftail[idx * 16] = run;
            run += bhist[idx];
        }
    }
    if (t == 255) boff[NB] = run;    // == E
    __syncthreads();
    if (t < NC) {
        int f0 = t << 5;
        ctail[t * 16] = boff[f0 < NB ? f0 : NB];
    }
}

__global__ __launch_bounds__(256) void coarse_partition(
    const int* __restrict__ src, const int* __restrict__ dst,
    int* __restrict__ ctail, int* __restrict__ csrA, int E, int NC)
{
    __shared__ int lhist[64], lcur[64], gpos[64];
    const int t = threadIdx.x;
    if (t < 64) { lhist[t] = 0; lcur[t] = 0; }
    __syncthreads();
    const int base = blockIdx.x * PCHUNK;
    int bb[32], pp[32];
#pragma unroll
    for (int i = 0; i < 32; ++i) {
        int e = base + i * 256 + t;
        bb[i] = -1;
        if (e < E) {
            int sv = src[e], dv = dst[e];
            bb[i] = dv >> CSH;
            pp[i] = (sv << CSH) | (dv & ((1 << CSH) - 1));
            atomicAdd(&lhist[bb[i]], 1);
        }
    }
    __syncthreads();
    if (t < NC && lhist[t]) gpos[t] = atomicAdd(&ctail[t * 16], lhist[t]);
    __syncthreads();
#pragma unroll
    for (int i = 0; i < 32; ++i) {
        if (bb[i] >= 0) {
            int b = bb[i];
            csrA[gpos[b] + atomicAdd(&lcur[b], 1)] = pp[i];
        }
    }
}

__global__ __launch_bounds__(256) void fine_partition(
    const int* __restrict__ csrA, const int* __restrict__ boff,
    int* __restrict__ ftail, int* __restrict__ csrB, int NB)
{
    __shared__ int lhist[32], lcur[32], gpos[32];
    const int b = blockIdx.x;
    const int t = threadIdx.x;
    const int f0 = b << 5;
    const int fe = (f0 + 32 < NB) ? f0 + 32 : NB;
    const int cstart = boff[f0 < NB ? f0 : NB];
    const int cend = boff[fe];
    const int start = cstart + blockIdx.y * PCHUNK;
    if (start >= cend) return;
    const int end = (start + PCHUNK < cend) ? start + PCHUNK : cend;
    if (t < 32) { lhist[t] = 0; lcur[t] = 0; }
    __syncthreads();
    int ff[32], pp[32];
#pragma unroll
    for (int i = 0; i < 32; ++i) {
        int e = start + i * 256 + t;
        ff[i] = -1;
        if (e < end) {
            int v = csrA[e];
            int sv = v >> CSH, dl = v & ((1 << CSH) - 1);
            ff[i] = dl >> BSH;
            pp[i] = (sv << BSH) | (dl & (BR - 1));
            atomicAdd(&lhist[ff[i]], 1);
        }
    }
    __syncthreads();
    if (t < 32 && lhist[t]) gpos[t] = atomicAdd(&ftail[(f0 + t) * 16], lhist[t]);
    __syncthreads();
#pragma unroll
    for (int i = 0; i < 32; ++i) {
        if (ff[i] >= 0) {
            int f = ff[i];
            csrB[gpos[f] + atomicAdd(&lcur[f], 1)] = pp[i];
        }
    }
}

__global__ __launch_bounds__(256) void bucket_build(
    int* __restrict__ csr, const int* __restrict__ boff,
    int* __restrict__ off, int N, int NB)
{
    __shared__ int ebuf[EBUF_CAP];
    __shared__ int lcnt[BR];
    __shared__ int lpref[BR];
    const int bi = blockIdx.x;
    const int t = threadIdx.x;
    const int nb0 = bi << BSH;
    const int p0 = boff[bi];
    const int p1 = boff[bi + 1];
    const int cnt = p1 - p0;

    if (t < BR) lcnt[t] = 0;
    __syncthreads();
    for (int i = t; i < cnt; i += 256) {
        int v = csr[p0 + i];
        if (i < EBUF_CAP) ebuf[i] = v;
        atomicAdd(&lcnt[v & (BR - 1)], 1);
    }
    __syncthreads();
    if (t < BR) {
        int c = lcnt[t];
        int sc = c;
#pragma unroll
        for (int ofs = 1; ofs < BR; ofs <<= 1) {
            int o = __shfl_up(sc, ofs);
            if (t >= ofs) sc += o;
        }
        lpref[t] = sc - c;
        int n = nb0 + t;
        if (n < N) off[n] = p0 + sc - c;
        lcnt[t] = 0;
    }
    if (bi == NB - 1 && t == 0) off[N] = p1;
    __syncthreads();
    for (int i = t; i < cnt && i < EBUF_CAP; i += 256) {
        int v = ebuf[i];
        int ln = v & (BR - 1);
        int p = atomicAdd(&lcnt[ln], 1);
        csr[p0 + lpref[ln] + p] = v >> BSH;
    }
}

// ---------------------------------------------------------------------------
// Pull-mode GAT aggregation over bf16 value rows.
// Per 64-edge chunk: lanes compute w in parallel into LDS (uint2 = {row byte
// offset, w}); gather phase uses F/2 lanes per row (2 bf16 per lane), with
// 64/(F/2) edges in flight per wave. f32 accumulation throughout.
// ---------------------------------------------------------------------------
template <int F, bool RELU>
__global__ __launch_bounds__(256) void gat_aggregate(
    const int* __restrict__ csr, const int* __restrict__ off,
    const float* __restrict__ As, const float* __restrict__ Ad,
    const unsigned short* __restrict__ Hb, const float* __restrict__ bias,
    float* __restrict__ Out, int N)
{
    constexpr int LPR = F / 2;        // lanes per row
    constexpr int EPI = 64 / LPR;     // edges in flight
    constexpr unsigned RB = F * 2;    // row bytes

    __shared__ uint2 pr[4][64];
    const int wave = threadIdx.x >> 6;
    const int lane = threadIdx.x & 63;
    const int n = blockIdx.x * 4 + wave;
    if (n >= N) return;

    const int o0 = off[n];
    const int deg = off[n + 1] - o0;
    const float adn = Ad[n];
    const float eself = leaky(As[n] + adn);

    // phase 1: segment max (includes self-loop), lane-parallel
    float m = eself;
    for (int i = lane; i < deg; i += 64) {
        int s = csr[o0 + i];
        m = fmaxf(m, leaky(As[s] + adn));
    }
#pragma unroll
    for (int ofs = 32; ofs; ofs >>= 1) m = fmaxf(m, __shfl_xor(m, ofs));

    uint2* myp = pr[wave];
    const char* Hc = (const char*)Hb;
    const int sub = lane / LPR;
    const unsigned f4 = (unsigned)(lane & (LPR - 1)) * 4u;

    float2 acc = make_float2(0.f, 0.f);
    float denp = 0.f;

    for (int c = 0; c < deg; c += 64) {
        int i = c + lane;
        float w = 0.f; unsigned sb = 0;
        if (i < deg) {
            int s = csr[o0 + i];
            w = __expf(leaky(As[s] + adn) - m);
            sb = (unsigned)s * RB;
            denp += w;
        }
        myp[lane] = make_uint2(sb, __float_as_uint(w));
        int lim = (deg - c < 64) ? deg - c : 64;
        int j = sub;
        for (; j + 3 * EPI < lim; j += 4 * EPI) {
            uint2 p0 = myp[j], p1 = myp[j + EPI], p2 = myp[j + 2 * EPI], p3 = myp[j + 3 * EPI];
            unsigned q0 = *(const unsigned*)(Hc + p0.x + f4);
            unsigned q1 = *(const unsigned*)(Hc + p1.x + f4);
            unsigned q2 = *(const unsigned*)(Hc + p2.x + f4);
            unsigned q3 = *(const unsigned*)(Hc + p3.x + f4);
            float w0 = uf(p0.y), w1 = uf(p1.y), w2 = uf(p2.y), w3 = uf(p3.y);
            acc.x = fmaf(w0, bflo(q0), acc.x); acc.y = fmaf(w0, bfhi(q0), acc.y);
            acc.x = fmaf(w1, bflo(q1), acc.x); acc.y = fmaf(w1, bfhi(q1), acc.y);
            acc.x = fmaf(w2, bflo(q2), acc.x); acc.y = fmaf(w2, bfhi(q2), acc.y);
            acc.x = fmaf(w3, bflo(q3), acc.x); acc.y = fmaf(w3, bfhi(q3), acc.y);
        }
        for (; j < lim; j += EPI) {
            uint2 p = myp[j];
            unsigned q = *(const unsigned*)(Hc + p.x + f4);
            float w0 = uf(p.y);
            acc.x = fmaf(w0, bflo(q), acc.x);
            acc.y = fmaf(w0, bfhi(q), acc.y);
        }
    }

    // reduce partial acc across the EPI sub-groups (same f4, different sub)
#pragma unroll
    for (int ofs = 32; ofs >= LPR; ofs >>= 1) {
        acc.x += __shfl_xor(acc.x, ofs);
        acc.y += __shfl_xor(acc.y, ofs);
    }
    // reduce den across all 64 lanes
#pragma unroll
    for (int ofs = 1; ofs < 64; ofs <<= 1) denp += __shfl_xor(denp, ofs);

    // self-loop term + finalize
    float wsf = __expf(eself - m);
    unsigned qs = *(const unsigned*)(Hc + (size_t)n * RB + f4);
    acc.x = fmaf(wsf, bflo(qs), acc.x);
    acc.y = fmaf(wsf, bfhi(qs), acc.y);
    float den = denp + wsf;

    if (sub == 0) {
        int fi = (lane & (LPR - 1)) * 2;
        float vx = acc.x / den + bias[fi];
        float vy = acc.y / den + bias[fi + 1];
        if (RELU) { vx = fmaxf(vx, 0.f); vy = fmaxf(vy, 0.f); }
        *reinterpret_cast<float2*>(&Out[(size_t)n * F + fi]) = make_float2(vx, vy);
    }
}

// ---------------------------------------------------------------------------
extern "C" void kernel_launch(void* const* d_in, const int* in_sizes, int n_in,
                              void* d_out, int out_size, void* d_ws, size_t ws_size,
                              hipStream_t stream)
{
    const float* x   = (const float*)d_in[0];
    const int*   ei  = (const int*)d_in[1];   // [2, E] int32
    const float* W1  = (const float*)d_in[2];
    const float* a1s = (const float*)d_in[3];
    const float* a1d = (const float*)d_in[4];
    const float* b1  = (const float*)d_in[5];
    const float* W2  = (const float*)d_in[6];
    const float* a2s = (const float*)d_in[7];
    const float* a2d = (const float*)d_in[8];
    const float* b2  = (const float*)d_in[9];

    const int N = in_sizes[0] / 128;
    const int E = in_sizes[1] / 2;
    const int NB = (N + BR - 1) >> BSH;
    const int NC = (N + (1 << CSH) - 1) >> CSH;
    const int* src = ei;
    const int* dst = ei + E;
    float* out = (float*)d_out;

    // ---- workspace layout ----
    float* ws = (float*)d_ws;
    size_t o = 0;
    unsigned short* h1b = (unsigned short*)(ws + o); o += (size_t)N * 16;  // N*32 bf16
    float* h1a = ws + o; o += (size_t)N * 32;
    unsigned short* h2b = (unsigned short*)(ws + o); o += (size_t)N * 32;  // N*64 bf16
    float* as1 = ws + o; o += N;
    float* ad1 = ws + o; o += N;
    float* as2 = ws + o; o += N;
    float* ad2 = ws + o; o += N;
    int* ip = (int*)(ws + o);
    size_t io = 0;
    int* bhist = ip + io; io += NB;
    int* boff  = ip + io; io += (NB + 1);
    int* ftail = ip + io; io += (size_t)NB * 16;
    int* ctail = ip + io; io += (size_t)NC * 16;
    int* off   = ip + io; io += (N + 1);
    int* csrA  = ip + io; io += E;
    int* csrB  = ip + io; io += E;

    // per-call state init (graph-replay safe)
    hipMemsetAsync(bhist, 0, (size_t)NB * sizeof(int), stream);

    // ---- CSR build (by dst), shared by both layers ----
    bucket_hist<<<256, 256, 0, stream>>>(dst, bhist, E, NB);
    bucket_scan<<<1, 256, 0, stream>>>(bhist, boff, ftail, ctail, NB, NC);
    coarse_partition<<<(E + PCHUNK - 1) / PCHUNK, 256, 0, stream>>>(
        src, dst, ctail, csrA, E, NC);
    fine_partition<<<dim3(NC, 9), 256, 0, stream>>>(csrA, boff, ftail, csrB, NB);
    bucket_build<<<NB, 256, 0, stream>>>(csrB, boff, off, N, NB);

    const int gn = (N + 3) / 4;

    // ---- layer 1 (FIN=128 -> 32) ----
    gemm_rows<128, 32, 8, 3><<<(N + 31) / 32, 256, 0, stream>>>(
        x, W1, a1s, a1d, h1b, as1, ad1, N);
    gat_aggregate<32, true><<<gn, 256, 0, stream>>>(
        csrB, off, as1, ad1, h1b, b1, h1a, N);

    // ---- layer 2 (32 -> 64) ----
    gemm_rows<32, 64, 16, 4><<<(N + 15) / 16, 256, 0, stream>>>(
        h1a, W2, a2s, a2d, h2b, as2, ad2, N);
    gat_aggregate<64, false><<<gn, 256, 0, stream>>>(
        csrB, off, as2, ad2, h2b, b2, out, N);
}